// Round 11
// baseline (934.576 us; speedup 1.0000x reference)
//
#include <hip/hip_runtime.h>

#define EPSV 1e-5f
#define CLS_SZ (32768*6)
#define FWS_FLOATS ((size_t)196608 * 128)

// 128-row layout (mono fallback only)
#define AL(ch,row) (((ch)<<7) + ((row) ^ ((((ch)&15))<<3)))
// 64-row layout: [ch][row], 8-row-group XOR swizzle
#define AL64(ch,row) (((ch)<<6) + ((row) ^ ((((ch)&7))<<3)))

__device__ __forceinline__ float4 ld4(const float* p) { return *reinterpret_cast<const float4*>(p); }
__device__ __forceinline__ void st4(float* p, float4 v) { *reinterpret_cast<float4*>(p) = v; }

// ---------------- W register streaming (shared) ----------------
__device__ __forceinline__ void ldW2(const float* __restrict__ Wg, int k0, int jg4,
                                     float4 (&w0)[2], float4 (&w1)[2])
{
  #pragma unroll
  for (int kk = 0; kk < 2; ++kk) {
    w0[kk] = ld4(Wg + (k0 + kk)*128 + jg4);
    w1[kk] = ld4(Wg + (k0 + kk)*128 + 64 + jg4);
  }
}

// ---------------- 64-row gemm: 4 rows x 8 cols per thread ----------------
__device__ __forceinline__ void fma2_64(const float* X, int k0, int ag,
                                        const float4 (&w0)[2], const float4 (&w1)[2],
                                        float (&acc)[4][8])
{
  #pragma unroll
  for (int kk = 0; kk < 2; ++kk) {
    int k = k0 + kk;
    float4 x = ld4(X + (k<<6) + ((ag<<2) ^ ((k & 7)<<3)));
    float xv[4] = {x.x,x.y,x.z,x.w};
    float wv[8] = {w0[kk].x,w0[kk].y,w0[kk].z,w0[kk].w,
                   w1[kk].x,w1[kk].y,w1[kk].z,w1[kk].w};
    #pragma unroll
    for (int r = 0; r < 4; ++r)
      #pragma unroll
      for (int c2 = 0; c2 < 8; ++c2)
        acc[r][c2] = fmaf(xv[r], wv[c2], acc[r][c2]);
  }
}

__device__ __forceinline__ void gemmR64(const float* X, const float* __restrict__ Wg,
                                        float (&acc)[4][8], int ag, int jg4)
{
  float4 a0[2], a1[2], b0[2], b1[2];
  ldW2(Wg, 0, jg4, a0, a1);
  #pragma unroll 1
  for (int c = 0; c < 64; c += 2) {
    ldW2(Wg, (c+1)*2, jg4, b0, b1);
    fma2_64(X, c*2, ag, a0, a1, acc);
    if (c + 2 < 64) ldW2(Wg, (c+2)*2, jg4, a0, a1);
    fma2_64(X, (c+1)*2, ag, b0, b1, acc);
  }
}

// output-layer (pred L3): W [128][60]; cols jg*4..+3 (jg<15)
__device__ __forceinline__ void ldWo(const float* __restrict__ Wg, int k0, int jg,
                                     bool ldw, float4 (&w)[8])
{
  #pragma unroll
  for (int kk = 0; kk < 8; ++kk)
    w[kk] = ldw ? ld4(Wg + (k0 + kk)*60 + jg*4) : make_float4(0.f,0.f,0.f,0.f);
}

__device__ __forceinline__ void fmaWo64(const float* X, int k0, int ag,
                                        const float4 (&w)[8], float (&acc)[4][4])
{
  #pragma unroll
  for (int kk = 0; kk < 8; ++kk) {
    int k = k0 + kk;
    float4 x = ld4(X + (k<<6) + ((ag<<2) ^ ((k & 7)<<3)));
    float xv[4] = {x.x,x.y,x.z,x.w};
    float wv[4] = {w[kk].x,w[kk].y,w[kk].z,w[kk].w};
    #pragma unroll
    for (int r = 0; r < 4; ++r)
      #pragma unroll
      for (int c2 = 0; c2 < 4; ++c2)
        acc[r][c2] = fmaf(xv[r], wv[c2], acc[r][c2]);
  }
}

__device__ __forceinline__ void gemmWoR64(const float* X, const float* __restrict__ Wg,
                                          float (&acc)[4][4], int ag, int jg)
{
  const bool ldw = (jg < 15);
  float4 a[8], b[8];
  ldWo(Wg, 0, jg, ldw, a);
  #pragma unroll 1
  for (int c = 0; c < 16; c += 2) {
    ldWo(Wg, (c+1)*8, jg, ldw, b);
    fmaWo64(X, c*8, ag, a, acc);
    if (c + 2 < 16) ldWo(Wg, (c+2)*8, jg, ldw, a);
    fmaWo64(X, (c+1)*8, ag, b, acc);
  }
}

// ---------------- GroupNorm stats (64-row) — R3's exact value tree ----------------
__device__ __forceinline__ void gn_finish64(float* PS1, float* PS2, float* MEAN, float* RSTD, int tid)
{
  __syncthreads();
  if (tid < 64) {
    float a = 0.f, b = 0.f;
    #pragma unroll
    for (int j = 0; j < 4; ++j) { a += PS1[tid*4 + j]; b += PS2[tid*4 + j]; }
    float mu = a * 0.0078125f;
    float var = b * 0.0078125f - mu*mu;
    MEAN[tid] = mu;
    RSTD[tid] = rsqrtf(var + EPSV);
  }
  __syncthreads();
}

__device__ __forceinline__ void gn_reduce4_64(const float (&acc)[4][8], float* PS1, float* PS2,
                                              float* MEAN, float* RSTD, int ag, int jg, int tid)
{
  #pragma unroll
  for (int r = 0; r < 4; ++r) {
    float s = 0.f, q = 0.f;
    #pragma unroll
    for (int c = 0; c < 8; ++c) { float v = acc[r][c]; s += v; q += v*v; }
    s += __shfl_xor(s, 1, 64); q += __shfl_xor(q, 1, 64);
    s += __shfl_xor(s, 2, 64); q += __shfl_xor(q, 2, 64);
    if ((jg & 3) == 0) { int row = ag*4 + r; PS1[row*4 + (jg>>2)] = s; PS2[row*4 + (jg>>2)] = q; }
  }
  gn_finish64(PS1, PS2, MEAN, RSTD, tid);
}

// ---------------- Kernel A: per-mode pred heads -> unsorted reg ----------------
// LDS: 32768 + 2048 + 512 = 35328 B -> 4 blocks/CU
__global__ void __launch_bounds__(256, 4) pred_kernel(
    const float* __restrict__ actors, const float* __restrict__ ctrs,
    const float* __restrict__ W1, const float* __restrict__ g1v, const float* __restrict__ b1v,
    const float* __restrict__ W2, const float* __restrict__ g2v, const float* __restrict__ b2v,
    const float* __restrict__ Wo, const float* __restrict__ bov,
    float* __restrict__ out_reg)
{
  __shared__ __align__(16) float ACT[8192];
  __shared__ float PS1[256], PS2[256], MEAN[64], RSTD[64];

  const int tid = threadIdx.x;
  const int jg = tid & 15, ag = tid >> 4;   // rows ag*4..+3, ag in 0..15
  const int jg4 = jg*4;
  const int m  = blockIdx.y;
  const int n0 = blockIdx.x * 64;

  // stage actors tile: row-per-lane (LDS conflict-free; global gathers hit L1/L2)
  #pragma unroll
  for (int p = 0; p < 8; ++p) {
    int i = (p<<8) + tid;
    int r = i & 63, ch0 = (i >> 6) << 2;
    float4 v = ld4(actors + (size_t)(n0 + r)*128 + ch0);
    ACT[AL64(ch0+0, r)] = v.x; ACT[AL64(ch0+1, r)] = v.y;
    ACT[AL64(ch0+2, r)] = v.z; ACT[AL64(ch0+3, r)] = v.w;
  }
  __syncthreads();

  float acc[4][8];
  #pragma unroll
  for (int r = 0; r < 4; ++r)
    #pragma unroll
    for (int c = 0; c < 8; ++c) acc[r][c] = 0.f;

  // L1: relu(GN(actors @ W1)) -> ACT
  gemmR64(ACT, W1 + (size_t)m*16384, acc, ag, jg4);
  gn_reduce4_64(acc, PS1, PS2, MEAN, RSTD, ag, jg, tid);
  {
    float mu[4], rs[4];
    #pragma unroll
    for (int r = 0; r < 4; ++r) { mu[r] = MEAN[ag*4+r]; rs[r] = RSTD[ag*4+r]; }
    float4 gl = ld4(g1v + m*128 + jg4), gh = ld4(g1v + m*128 + 64 + jg4);
    float4 bl = ld4(b1v + m*128 + jg4), bh = ld4(b1v + m*128 + 64 + jg4);
    float gv[8] = {gl.x,gl.y,gl.z,gl.w,gh.x,gh.y,gh.z,gh.w};
    float bv[8] = {bl.x,bl.y,bl.z,bl.w,bh.x,bh.y,bh.z,bh.w};
    float vm[4][8];
    #pragma unroll
    for (int r = 0; r < 4; ++r)
      #pragma unroll
      for (int c = 0; c < 8; ++c)
        vm[r][c] = fmaxf((acc[r][c] - mu[r]) * rs[r] * gv[c] + bv[c], 0.f);
    #pragma unroll
    for (int c = 0; c < 8; ++c) {
      int ch = (c < 4) ? (jg4 + c) : (64 + jg4 + (c - 4));
      st4(ACT + AL64(ch, ag*4), make_float4(vm[0][c],vm[1][c],vm[2][c],vm[3][c]));
    }
  }
  __syncthreads();

  #pragma unroll
  for (int r = 0; r < 4; ++r)
    #pragma unroll
    for (int c = 0; c < 8; ++c) acc[r][c] = 0.f;

  // L2: relu(GN(h1 @ W2) + actors) -> ACT
  gemmR64(ACT, W2 + (size_t)m*16384, acc, ag, jg4);
  gn_reduce4_64(acc, PS1, PS2, MEAN, RSTD, ag, jg, tid);
  {
    float mu[4], rs[4];
    #pragma unroll
    for (int r = 0; r < 4; ++r) { mu[r] = MEAN[ag*4+r]; rs[r] = RSTD[ag*4+r]; }
    float4 gl = ld4(g2v + m*128 + jg4), gh = ld4(g2v + m*128 + 64 + jg4);
    float4 bl = ld4(b2v + m*128 + jg4), bh = ld4(b2v + m*128 + 64 + jg4);
    float gv[8] = {gl.x,gl.y,gl.z,gl.w,gh.x,gh.y,gh.z,gh.w};
    float bv[8] = {bl.x,bl.y,bl.z,bl.w,bh.x,bh.y,bh.z,bh.w};
    float vm[4][8];
    #pragma unroll
    for (int r = 0; r < 4; ++r) {
      const float* ap = actors + (size_t)(n0 + ag*4 + r)*128;
      float4 a0 = ld4(ap + jg4), a1 = ld4(ap + 64 + jg4);
      float av[8] = {a0.x,a0.y,a0.z,a0.w,a1.x,a1.y,a1.z,a1.w};
      #pragma unroll
      for (int c = 0; c < 8; ++c)
        vm[r][c] = fmaxf((acc[r][c] - mu[r]) * rs[r] * gv[c] + bv[c] + av[c], 0.f);
    }
    #pragma unroll
    for (int c = 0; c < 8; ++c) {
      int ch = (c < 4) ? (jg4 + c) : (64 + jg4 + (c - 4));
      st4(ACT + AL64(ch, ag*4), make_float4(vm[0][c],vm[1][c],vm[2][c],vm[3][c]));
    }
  }
  __syncthreads();

  // L3: h @ Wo + bo + ctr -> reg
  float acc2[4][4];
  #pragma unroll
  for (int r = 0; r < 4; ++r)
    #pragma unroll
    for (int c = 0; c < 4; ++c) acc2[r][c] = 0.f;
  gemmWoR64(ACT, Wo + (size_t)m*7680, acc2, ag, jg);

  if (jg < 15) {
    float4 bo4 = ld4(bov + m*60 + jg4);
    #pragma unroll
    for (int r = 0; r < 4; ++r) {
      int n = n0 + ag*4 + r;
      float2 cc = *reinterpret_cast<const float2*>(ctrs + 2*n);
      float4 v;
      v.x = acc2[r][0] + bo4.x + cc.x;
      v.y = acc2[r][1] + bo4.y + cc.y;
      v.z = acc2[r][2] + bo4.z + cc.x;
      v.w = acc2[r][3] + bo4.w + cc.y;
      st4(out_reg + (size_t)n*360 + m*60 + jg4, v);
    }
  }
}

// ---------------- Kernel B1: AttDest -> feats (to workspace) ----------------
__global__ void __launch_bounds__(256, 4) att_feats_kernel(
    const float* __restrict__ actors, const float* __restrict__ ctrs,
    const float* __restrict__ dW1, const float* __restrict__ db1,
    const float* __restrict__ dW2, const float* __restrict__ dg2, const float* __restrict__ db2,
    const float* __restrict__ aW, const float* __restrict__ aG, const float* __restrict__ aB,
    const float* __restrict__ reg, float* __restrict__ fws)
{
  __shared__ __align__(16) float ACT[8192];
  __shared__ float PS1[256], PS2[256], MEAN[64], RSTD[64];
  float* D0x = MEAN;   // lifetimes disjoint (consumed in P1; MEAN written in P2 gn)
  float* D0y = RSTD;

  const int tid = threadIdx.x;
  const int jg = tid & 15, ag = tid >> 4;
  const int jg4 = jg*4;
  const int r0 = blockIdx.x * 64;

  // P0: dist0 = ctr - reg_last
  if (tid < 64) {
    int rg = r0 + tid;
    int n = rg / 6, mm = rg - 6*n;
    size_t base = (size_t)n*360 + mm*60;
    float2 c2 = *reinterpret_cast<const float2*>(ctrs + 2*n);
    D0x[tid] = c2.x - reg[base + 58];
    D0y[tid] = c2.y - reg[base + 59];
  }
  __syncthreads();

  // P1: dist1 = relu(dist0 @ dW1 + db1) -> ACT
  {
    float dx[4], dy[4];
    #pragma unroll
    for (int r = 0; r < 4; ++r) { dx[r] = D0x[ag*4+r]; dy[r] = D0y[ag*4+r]; }
    #pragma unroll
    for (int c = 0; c < 8; ++c) {
      int ch = (c < 4) ? (jg4 + c) : (64 + jg4 + (c - 4));
      float w1 = dW1[ch], w2 = dW1[128 + ch], bb = db1[ch];
      float4 v;
      v.x = fmaxf(fmaf(dx[0], w1, fmaf(dy[0], w2, bb)), 0.f);
      v.y = fmaxf(fmaf(dx[1], w1, fmaf(dy[1], w2, bb)), 0.f);
      v.z = fmaxf(fmaf(dx[2], w1, fmaf(dy[2], w2, bb)), 0.f);
      v.w = fmaxf(fmaf(dx[3], w1, fmaf(dy[3], w2, bb)), 0.f);
      st4(ACT + AL64(ch, ag*4), v);
    }
  }
  __syncthreads();

  float acc[4][8];
  #pragma unroll
  for (int r = 0; r < 4; ++r)
    #pragma unroll
    for (int c = 0; c < 8; ++c) acc[r][c] = 0.f;

  // P2: dist2 = relu(GN(dist1 @ dW2)) -> ACT
  gemmR64(ACT, dW2, acc, ag, jg4);
  gn_reduce4_64(acc, PS1, PS2, MEAN, RSTD, ag, jg, tid);
  {
    float mu[4], rs[4];
    #pragma unroll
    for (int r = 0; r < 4; ++r) { mu[r] = MEAN[ag*4+r]; rs[r] = RSTD[ag*4+r]; }
    float4 gl = ld4(dg2 + jg4), gh = ld4(dg2 + 64 + jg4);
    float4 bl = ld4(db2 + jg4), bh = ld4(db2 + 64 + jg4);
    float gv[8] = {gl.x,gl.y,gl.z,gl.w,gh.x,gh.y,gh.z,gh.w};
    float bv[8] = {bl.x,bl.y,bl.z,bl.w,bh.x,bh.y,bh.z,bh.w};
    float vm[4][8];
    #pragma unroll
    for (int r = 0; r < 4; ++r)
      #pragma unroll
      for (int c = 0; c < 8; ++c)
        vm[r][c] = fmaxf((acc[r][c] - mu[r]) * rs[r] * gv[c] + bv[c], 0.f);
    #pragma unroll
    for (int c = 0; c < 8; ++c) {
      int ch = (c < 4) ? (jg4 + c) : (64 + jg4 + (c - 4));
      st4(ACT + AL64(ch, ag*4), make_float4(vm[0][c],vm[1][c],vm[2][c],vm[3][c]));
    }
  }
  __syncthreads();

  // P3: feats = relu(GN(dist2 @ aW_lo + agts @ aW_hi)) -> fws
  #pragma unroll
  for (int r = 0; r < 4; ++r)
    #pragma unroll
    for (int c = 0; c < 8; ++c) acc[r][c] = 0.f;
  gemmR64(ACT, aW, acc, ag, jg4);
  __syncthreads();                 // all waves done reading dist2
  #pragma unroll
  for (int p = 0; p < 8; ++p) {
    int i = (p<<8) + tid;
    int r = i & 63, ch0 = (i >> 6) << 2;
    int n = (r0 + r) / 6;
    float4 v = ld4(actors + (size_t)n*128 + ch0);
    ACT[AL64(ch0+0, r)] = v.x; ACT[AL64(ch0+1, r)] = v.y;
    ACT[AL64(ch0+2, r)] = v.z; ACT[AL64(ch0+3, r)] = v.w;
  }
  __syncthreads();                 // agts staged
  gemmR64(ACT, aW + 16384, acc, ag, jg4);
  gn_reduce4_64(acc, PS1, PS2, MEAN, RSTD, ag, jg, tid);
  {
    float mu[4], rs[4];
    #pragma unroll
    for (int r = 0; r < 4; ++r) { mu[r] = MEAN[ag*4+r]; rs[r] = RSTD[ag*4+r]; }
    float4 gl = ld4(aG + jg4), gh = ld4(aG + 64 + jg4);
    float4 bl = ld4(aB + jg4), bh = ld4(aB + 64 + jg4);
    float gv[8] = {gl.x,gl.y,gl.z,gl.w,gh.x,gh.y,gh.z,gh.w};
    float bv[8] = {bl.x,bl.y,bl.z,bl.w,bh.x,bh.y,bh.z,bh.w};
    #pragma unroll
    for (int r = 0; r < 4; ++r) {
      float fv[8];
      #pragma unroll
      for (int c = 0; c < 8; ++c)
        fv[c] = fmaxf((acc[r][c] - mu[r]) * rs[r] * gv[c] + bv[c], 0.f);
      float* fp = fws + (size_t)(r0 + ag*4 + r)*128;
      st4(fp + jg4,      make_float4(fv[0],fv[1],fv[2],fv[3]));
      st4(fp + 64 + jg4, make_float4(fv[4],fv[5],fv[6],fv[7]));
    }
  }
}

// ---------------- Kernel B2: cls head from feats(ws) -> unsorted cls ----------------
__global__ void __launch_bounds__(256, 4) att_cls2_kernel(
    const float* __restrict__ cW1, const float* __restrict__ cg1, const float* __restrict__ cb1,
    const float* __restrict__ cW2, const float* __restrict__ cg2, const float* __restrict__ cb2,
    const float* __restrict__ cWo, const float* __restrict__ cbo,
    const float* __restrict__ fws, float* __restrict__ cls_out)
{
  __shared__ __align__(16) float ACT[8192];
  __shared__ float PS1[256], PS2[256], MEAN[64], RSTD[64];

  const int tid = threadIdx.x;
  const int jg = tid & 15, ag = tid >> 4;
  const int jg4 = jg*4;
  const int r0 = blockIdx.x * 64;

  #pragma unroll
  for (int p = 0; p < 8; ++p) {
    int i = (p<<8) + tid;
    int r = i & 63, ch0 = (i >> 6) << 2;
    float4 v = ld4(fws + (size_t)(r0 + r)*128 + ch0);
    ACT[AL64(ch0+0, r)] = v.x; ACT[AL64(ch0+1, r)] = v.y;
    ACT[AL64(ch0+2, r)] = v.z; ACT[AL64(ch0+3, r)] = v.w;
  }
  __syncthreads();

  float acc[4][8];
  #pragma unroll
  for (int r = 0; r < 4; ++r)
    #pragma unroll
    for (int c = 0; c < 8; ++c) acc[r][c] = 0.f;

  // P4: c1 = relu(GN(feats @ cls_W1)) -> ACT
  gemmR64(ACT, cW1, acc, ag, jg4);
  gn_reduce4_64(acc, PS1, PS2, MEAN, RSTD, ag, jg, tid);
  {
    float mu[4], rs[4];
    #pragma unroll
    for (int r = 0; r < 4; ++r) { mu[r] = MEAN[ag*4+r]; rs[r] = RSTD[ag*4+r]; }
    float4 gl = ld4(cg1 + jg4), gh = ld4(cg1 + 64 + jg4);
    float4 bl = ld4(cb1 + jg4), bh = ld4(cb1 + 64 + jg4);
    float gv[8] = {gl.x,gl.y,gl.z,gl.w,gh.x,gh.y,gh.z,gh.w};
    float bv[8] = {bl.x,bl.y,bl.z,bl.w,bh.x,bh.y,bh.z,bh.w};
    float vm[4][8];
    #pragma unroll
    for (int r = 0; r < 4; ++r)
      #pragma unroll
      for (int c = 0; c < 8; ++c)
        vm[r][c] = fmaxf((acc[r][c] - mu[r]) * rs[r] * gv[c] + bv[c], 0.f);
    #pragma unroll
    for (int c = 0; c < 8; ++c) {
      int ch = (c < 4) ? (jg4 + c) : (64 + jg4 + (c - 4));
      st4(ACT + AL64(ch, ag*4), make_float4(vm[0][c],vm[1][c],vm[2][c],vm[3][c]));
    }
  }
  __syncthreads();

  // P5: c2 = GN(c1 @ cls_W2); c = relu(c2 + feats); cls = c @ cls_Wo + bo
  #pragma unroll
  for (int r = 0; r < 4; ++r)
    #pragma unroll
    for (int c = 0; c < 8; ++c) acc[r][c] = 0.f;
  gemmR64(ACT, cW2, acc, ag, jg4);
  gn_reduce4_64(acc, PS1, PS2, MEAN, RSTD, ag, jg, tid);
  {
    float mu[4], rs[4];
    #pragma unroll
    for (int r = 0; r < 4; ++r) { mu[r] = MEAN[ag*4+r]; rs[r] = RSTD[ag*4+r]; }
    float4 gl = ld4(cg2 + jg4), gh = ld4(cg2 + 64 + jg4);
    float4 bl = ld4(cb2 + jg4), bh = ld4(cb2 + 64 + jg4);
    float4 wl = ld4(cWo + jg4), wh = ld4(cWo + 64 + jg4);
    float gv[8] = {gl.x,gl.y,gl.z,gl.w,gh.x,gh.y,gh.z,gh.w};
    float bv[8] = {bl.x,bl.y,bl.z,bl.w,bh.x,bh.y,bh.z,bh.w};
    float wv[8] = {wl.x,wl.y,wl.z,wl.w,wh.x,wh.y,wh.z,wh.w};
    #pragma unroll
    for (int r = 0; r < 4; ++r) {
      const float* fp = fws + (size_t)(r0 + ag*4 + r)*128;
      float4 a0 = ld4(fp + jg4), a1 = ld4(fp + 64 + jg4);
      float av[8] = {a0.x,a0.y,a0.z,a0.w,a1.x,a1.y,a1.z,a1.w};
      float p = 0.f;
      #pragma unroll
      for (int c = 0; c < 8; ++c) {
        float v = (acc[r][c] - mu[r]) * rs[r] * gv[c] + bv[c];
        v = fmaxf(v + av[c], 0.f);
        p = fmaf(v, wv[c], p);
      }
      float s = p;
      s += __shfl_xor(s, 1, 64);
      s += __shfl_xor(s, 2, 64);
      if ((jg & 3) == 0) PS1[(ag*4+r)*4 + (jg>>2)] = s;
    }
  }
  __syncthreads();
  if (tid < 64) {
    float s = 0.f;
    #pragma unroll
    for (int j = 0; j < 4; ++j) s += PS1[tid*4 + j];
    cls_out[r0 + tid] = s + cbo[0];
  }
}

// ---------------- Fallback: monolithic att (128-row gemmR), if ws too small ----------------
__device__ __forceinline__ void fma2(const float* X, int k0, int ag,
                                     const float4 (&w0)[2], const float4 (&w1)[2],
                                     float (&acc)[8][8])
{
  #pragma unroll
  for (int kk = 0; kk < 2; ++kk) {
    int k = k0 + kk;
    const float* xp = X + (k<<7) + ((ag<<3) ^ ((k & 15)<<3));
    float4 x0 = ld4(xp), x1 = ld4(xp + 4);
    float xv[8] = {x0.x,x0.y,x0.z,x0.w,x1.x,x1.y,x1.z,x1.w};
    float wv[8] = {w0[kk].x,w0[kk].y,w0[kk].z,w0[kk].w,
                   w1[kk].x,w1[kk].y,w1[kk].z,w1[kk].w};
    #pragma unroll
    for (int r = 0; r < 8; ++r)
      #pragma unroll
      for (int c2 = 0; c2 < 8; ++c2)
        acc[r][c2] = fmaf(xv[r], wv[c2], acc[r][c2]);
  }
}

__device__ __forceinline__ void gemmR(const float* X, const float* __restrict__ Wg,
                                      float (&acc)[8][8], int ag, int jg4)
{
  float4 a0[2], a1[2], b0[2], b1[2];
  ldW2(Wg, 0, jg4, a0, a1);
  #pragma unroll 1
  for (int c = 0; c < 64; c += 2) {
    ldW2(Wg, (c+1)*2, jg4, b0, b1);
    fma2(X, c*2, ag, a0, a1, acc);
    if (c + 2 < 64) ldW2(Wg, (c+2)*2, jg4, a0, a1);
    fma2(X, (c+1)*2, ag, b0, b1, acc);
  }
}

__device__ __forceinline__ void gn_finish128(float* PS1, float* PS2, float* MEAN, float* RSTD, int tid)
{
  __syncthreads();
  if (tid < 128) {
    float a = 0.f, b = 0.f;
    #pragma unroll
    for (int j = 0; j < 4; ++j) { a += PS1[tid*4 + j]; b += PS2[tid*4 + j]; }
    float mu = a * 0.0078125f;
    float var = b * 0.0078125f - mu*mu;
    MEAN[tid] = mu;
    RSTD[tid] = rsqrtf(var + EPSV);
  }
  __syncthreads();
}

__device__ __forceinline__ void gn_reduce8(const float (&acc)[8][8], float* PS1, float* PS2,
                                           float* MEAN, float* RSTD, int ag, int jg, int tid)
{
  #pragma unroll
  for (int r = 0; r < 8; ++r) {
    float s = 0.f, q = 0.f;
    #pragma unroll
    for (int c = 0; c < 8; ++c) { float v = acc[r][c]; s += v; q += v*v; }
    s += __shfl_xor(s, 1, 64); q += __shfl_xor(q, 1, 64);
    s += __shfl_xor(s, 2, 64); q += __shfl_xor(q, 2, 64);
    if ((jg & 3) == 0) { int row = ag*8 + r; PS1[row*4 + (jg>>2)] = s; PS2[row*4 + (jg>>2)] = q; }
  }
  gn_finish128(PS1, PS2, MEAN, RSTD, tid);
}

__global__ void __launch_bounds__(256, 2) att_cls_mono_kernel(
    const float* __restrict__ actors, const float* __restrict__ ctrs,
    const float* __restrict__ dW1, const float* __restrict__ db1,
    const float* __restrict__ dW2, const float* __restrict__ dg2, const float* __restrict__ db2,
    const float* __restrict__ aW, const float* __restrict__ aG, const float* __restrict__ aB,
    const float* __restrict__ cW1, const float* __restrict__ cg1, const float* __restrict__ cb1,
    const float* __restrict__ cW2, const float* __restrict__ cg2, const float* __restrict__ cb2,
    const float* __restrict__ cWo, const float* __restrict__ cbo,
    const float* __restrict__ reg, float* __restrict__ cls_out)
{
  __shared__ __align__(16) float ACT[16384];
  __shared__ float PS1[512], PS2[512], MEAN[128], RSTD[128];
  float* D0x = MEAN;
  float* D0y = RSTD;

  const int tid = threadIdx.x;
  const int jg = tid & 15, ag = tid >> 4;
  const int jg4 = jg*4;
  const int r0 = blockIdx.x * 128;

  if (tid < 128) {
    int rg = r0 + tid;
    int n = rg / 6, mm = rg - 6*n;
    size_t base = (size_t)n*360 + mm*60;
    float2 c2 = *reinterpret_cast<const float2*>(ctrs + 2*n);
    D0x[tid] = c2.x - reg[base + 58];
    D0y[tid] = c2.y - reg[base + 59];
  }
  __syncthreads();

  {
    float dx[8], dy[8];
    #pragma unroll
    for (int r = 0; r < 8; ++r) { dx[r] = D0x[ag*8+r]; dy[r] = D0y[ag*8+r]; }
    #pragma unroll
    for (int c = 0; c < 8; ++c) {
      int ch = (c < 4) ? (jg4 + c) : (64 + jg4 + (c - 4));
      float w1 = dW1[ch], w2 = dW1[128 + ch], bb = db1[ch];
      float v[8];
      #pragma unroll
      for (int r = 0; r < 8; ++r) v[r] = fmaxf(fmaf(dx[r], w1, fmaf(dy[r], w2, bb)), 0.f);
      int base = (ch<<7) + ((ag<<3) ^ ((ch & 15)<<3));
      st4(ACT + base,     make_float4(v[0],v[1],v[2],v[3]));
      st4(ACT + base + 4, make_float4(v[4],v[5],v[6],v[7]));
    }
  }
  __syncthreads();

  float acc[8][8];
  #pragma unroll
  for (int r = 0; r < 8; ++r)
    #pragma unroll
    for (int c = 0; c < 8; ++c) acc[r][c] = 0.f;

  gemmR(ACT, dW2, acc, ag, jg4);
  gn_reduce8(acc, PS1, PS2, MEAN, RSTD, ag, jg, tid);
  {
    float mu[8], rs[8];
    #pragma unroll
    for (int r = 0; r < 8; ++r) { mu[r] = MEAN[ag*8+r]; rs[r] = RSTD[ag*8+r]; }
    float4 gl = ld4(dg2 + jg4), gh = ld4(dg2 + 64 + jg4);
    float4 bl = ld4(db2 + jg4), bh = ld4(db2 + 64 + jg4);
    float gv[8] = {gl.x,gl.y,gl.z,gl.w,gh.x,gh.y,gh.z,gh.w};
    float bv[8] = {bl.x,bl.y,bl.z,bl.w,bh.x,bh.y,bh.z,bh.w};
    float vm[8][8];
    #pragma unroll
    for (int r = 0; r < 8; ++r)
      #pragma unroll
      for (int c = 0; c < 8; ++c)
        vm[r][c] = fmaxf((acc[r][c] - mu[r]) * rs[r] * gv[c] + bv[c], 0.f);
    #pragma unroll
    for (int c = 0; c < 8; ++c) {
      int ch = (c < 4) ? (jg4 + c) : (64 + jg4 + (c - 4));
      int base = (ch<<7) + ((ag<<3) ^ ((ch & 15)<<3));
      st4(ACT + base,     make_float4(vm[0][c],vm[1][c],vm[2][c],vm[3][c]));
      st4(ACT + base + 4, make_float4(vm[4][c],vm[5][c],vm[6][c],vm[7][c]));
    }
  }
  __syncthreads();

  #pragma unroll
  for (int r = 0; r < 8; ++r)
    #pragma unroll
    for (int c = 0; c < 8; ++c) acc[r][c] = 0.f;
  gemmR(ACT, aW, acc, ag, jg4);
  __syncthreads();
  #pragma unroll
  for (int p = 0; p < 16; ++p) {
    int i = (p<<8) + tid;
    int r = i >> 5, q4 = (i & 31) << 2;
    int n = (r0 + r) / 6;
    float4 v = ld4(actors + (size_t)n*128 + q4);
    ACT[AL(q4+0, r)] = v.x; ACT[AL(q4+1, r)] = v.y;
    ACT[AL(q4+2, r)] = v.z; ACT[AL(q4+3, r)] = v.w;
  }
  __syncthreads();
  gemmR(ACT, aW + 16384, acc, ag, jg4);
  gn_reduce8(acc, PS1, PS2, MEAN, RSTD, ag, jg, tid);
  float feats[8][8];
  {
    float mu[8], rs[8];
    #pragma unroll
    for (int r = 0; r < 8; ++r) { mu[r] = MEAN[ag*8+r]; rs[r] = RSTD[ag*8+r]; }
    float4 gl = ld4(aG + jg4), gh = ld4(aG + 64 + jg4);
    float4 bl = ld4(aB + jg4), bh = ld4(aB + 64 + jg4);
    float gv[8] = {gl.x,gl.y,gl.z,gl.w,gh.x,gh.y,gh.z,gh.w};
    float bv[8] = {bl.x,bl.y,bl.z,bl.w,bh.x,bh.y,bh.z,bh.w};
    #pragma unroll
    for (int r = 0; r < 8; ++r)
      #pragma unroll
      for (int c = 0; c < 8; ++c)
        feats[r][c] = fmaxf((acc[r][c] - mu[r]) * rs[r] * gv[c] + bv[c], 0.f);
    #pragma unroll
    for (int c = 0; c < 8; ++c) {
      int ch = (c < 4) ? (jg4 + c) : (64 + jg4 + (c - 4));
      int base = (ch<<7) + ((ag<<3) ^ ((ch & 15)<<3));
      st4(ACT + base,     make_float4(feats[0][c],feats[1][c],feats[2][c],feats[3][c]));
      st4(ACT + base + 4, make_float4(feats[4][c],feats[5][c],feats[6][c],feats[7][c]));
    }
  }
  __syncthreads();

  #pragma unroll
  for (int r = 0; r < 8; ++r)
    #pragma unroll
    for (int c = 0; c < 8; ++c) acc[r][c] = 0.f;
  gemmR(ACT, cW1, acc, ag, jg4);
  gn_reduce8(acc, PS1, PS2, MEAN, RSTD, ag, jg, tid);
  {
    float mu[8], rs[8];
    #pragma unroll
    for (int r = 0; r < 8; ++r) { mu[r] = MEAN[ag*8+r]; rs[r] = RSTD[ag*8+r]; }
    float4 gl = ld4(cg1 + jg4), gh = ld4(cg1 + 64 + jg4);
    float4 bl = ld4(cb1 + jg4), bh = ld4(cb1 + 64 + jg4);
    float gv[8] = {gl.x,gl.y,gl.z,gl.w,gh.x,gh.y,gh.z,gh.w};
    float bv[8] = {bl.x,bl.y,bl.z,bl.w,bh.x,bh.y,bh.z,bh.w};
    float vm[8][8];
    #pragma unroll
    for (int r = 0; r < 8; ++r)
      #pragma unroll
      for (int c = 0; c < 8; ++c)
        vm[r][c] = fmaxf((acc[r][c] - mu[r]) * rs[r] * gv[c] + bv[c], 0.f);
    #pragma unroll
    for (int c = 0; c < 8; ++c) {
      int ch = (c < 4) ? (jg4 + c) : (64 + jg4 + (c - 4));
      int base = (ch<<7) + ((ag<<3) ^ ((ch & 15)<<3));
      st4(ACT + base,     make_float4(vm[0][c],vm[1][c],vm[2][c],vm[3][c]));
      st4(ACT + base + 4, make_float4(vm[4][c],vm[5][c],vm[6][c],vm[7][c]));
    }
  }
  __syncthreads();

  #pragma unroll
  for (int r = 0; r < 8; ++r)
    #pragma unroll
    for (int c = 0; c < 8; ++c) acc[r][c] = 0.f;
  gemmR(ACT, cW2, acc, ag, jg4);
  gn_reduce8(acc, PS1, PS2, MEAN, RSTD, ag, jg, tid);
  {
    float mu[8], rs[8], p[8];
    #pragma unroll
    for (int r = 0; r < 8; ++r) { mu[r] = MEAN[ag*8+r]; rs[r] = RSTD[ag*8+r]; p[r] = 0.f; }
    float4 gl = ld4(cg2 + jg4), gh = ld4(cg2 + 64 + jg4);
    float4 bl = ld4(cb2 + jg4), bh = ld4(cb2 + 64 + jg4);
    float4 wl = ld4(cWo + jg4), wh = ld4(cWo + 64 + jg4);
    float gv[8] = {gl.x,gl.y,gl.z,gl.w,gh.x,gh.y,gh.z,gh.w};
    float bv[8] = {bl.x,bl.y,bl.z,bl.w,bh.x,bh.y,bh.z,bh.w};
    float wv[8] = {wl.x,wl.y,wl.z,wl.w,wh.x,wh.y,wh.z,wh.w};
    #pragma unroll
    for (int c = 0; c < 8; ++c) {
      #pragma unroll
      for (int r = 0; r < 8; ++r) {
        float v = (acc[r][c] - mu[r]) * rs[r] * gv[c] + bv[c];
        v = fmaxf(v + feats[r][c], 0.f);
        p[r] = fmaf(v, wv[c], p[r]);
      }
    }
    #pragma unroll
    for (int r = 0; r < 8; ++r) {
      float s = p[r];
      s += __shfl_xor(s, 1, 64);
      s += __shfl_xor(s, 2, 64);
      if ((jg & 3) == 0) PS1[(ag*8+r)*4 + (jg>>2)] = s;
    }
  }
  __syncthreads();
  if (tid < 128) {
    float s = 0.f;
    #pragma unroll
    for (int j = 0; j < 4; ++j) s += PS1[tid*4 + j];
    cls_out[r0 + tid] = s + cbo[0];
  }
}

// ---------------- Kernel C: per-actor stable descending sort + permute ----------------
__global__ void __launch_bounds__(256) sort_kernel(float* __restrict__ out)
{
  __shared__ float RL[64*360];
  __shared__ float CL[64*6];
  __shared__ float CS[64*6];
  __shared__ int   ORD[64*6];

  const int tid = threadIdx.x;
  const int n0 = blockIdx.x * 64;
  float* regp = out + CLS_SZ;

  for (int i = tid; i < 64*360; i += 256) RL[i] = regp[(size_t)n0*360 + i];
  for (int i = tid; i < 384; i += 256)    CL[i] = out[n0*6 + i];
  __syncthreads();

  if (tid < 64) {
    float v[6];
    #pragma unroll
    for (int m2 = 0; m2 < 6; ++m2) v[m2] = CL[tid*6 + m2];
    int used = 0;
    for (int j = 0; j < 6; ++j) {
      int best = -1; float bv = 0.f;
      for (int m2 = 0; m2 < 6; ++m2) {
        if (used & (1 << m2)) continue;
        if (best < 0 || v[m2] > bv) { best = m2; bv = v[m2]; }  // stable: strict >
      }
      used |= (1 << best);
      ORD[tid*6 + j] = best;
      CS[tid*6 + j] = bv;
    }
  }
  __syncthreads();

  for (int i = tid; i < 384; i += 256) out[n0*6 + i] = CS[i];
  for (int i = tid; i < 64*360; i += 256) {
    int rl = i / 360, rem = i - rl*360;
    int slot = rem / 60, j = rem - slot*60;
    out[CLS_SZ + (size_t)n0*360 + i] = RL[rl*360 + ORD[rl*6 + slot]*60 + j];
  }
}

extern "C" void kernel_launch(void* const* d_in, const int* in_sizes, int n_in,
                              void* d_out, int out_size, void* d_ws, size_t ws_size,
                              hipStream_t stream)
{
  (void)in_sizes; (void)n_in; (void)out_size;
  const float* actors = (const float*)d_in[0];
  const float* ctrs   = (const float*)d_in[1];
  // d_in[2] = actor_idcs (identity partition; unused by the math)
  const float* pW1 = (const float*)d_in[3];
  const float* pg1 = (const float*)d_in[4];
  const float* pb1 = (const float*)d_in[5];
  const float* pW2 = (const float*)d_in[6];
  const float* pg2 = (const float*)d_in[7];
  const float* pb2 = (const float*)d_in[8];
  const float* pWo = (const float*)d_in[9];
  const float* pbo = (const float*)d_in[10];
  const float* cW1 = (const float*)d_in[11];
  const float* cg1 = (const float*)d_in[12];
  const float* cb1 = (const float*)d_in[13];
  const float* cW2 = (const float*)d_in[14];
  const float* cg2 = (const float*)d_in[15];
  const float* cb2 = (const float*)d_in[16];
  const float* cWo = (const float*)d_in[17];
  const float* cbo = (const float*)d_in[18];
  const float* dW1 = (const float*)d_in[19];
  const float* db1 = (const float*)d_in[20];
  const float* dW2 = (const float*)d_in[21];
  const float* dg2 = (const float*)d_in[22];
  const float* db2 = (const float*)d_in[23];
  const float* aW  = (const float*)d_in[24];
  const float* aG  = (const float*)d_in[25];
  const float* aB  = (const float*)d_in[26];

  float* out = (float*)d_out;
  float* out_reg = out + CLS_SZ;
  float* fws = (float*)d_ws;
  const bool split = ws_size >= FWS_FLOATS * sizeof(float);

  dim3 gA(512, 6);
  pred_kernel<<<gA, 256, 0, stream>>>(actors, ctrs, pW1, pg1, pb1, pW2, pg2, pb2,
                                      pWo, pbo, out_reg);
  if (split) {
    att_feats_kernel<<<3072, 256, 0, stream>>>(actors, ctrs,
                                               dW1, db1, dW2, dg2, db2,
                                               aW, aG, aB, out_reg, fws);
    att_cls2_kernel<<<3072, 256, 0, stream>>>(cW1, cg1, cb1, cW2, cg2, cb2,
                                              cWo, cbo, fws, out);
  } else {
    att_cls_mono_kernel<<<1536, 256, 0, stream>>>(actors, ctrs,
                                                  dW1, db1, dW2, dg2, db2,
                                                  aW, aG, aB,
                                                  cW1, cg1, cb1, cW2, cg2, cb2, cWo, cbo,
                                                  out_reg, out);
  }
  sort_kernel<<<512, 256, 0, stream>>>(out);
}

// Round 12
// 820.458 us; speedup vs baseline: 1.1391x; 1.1391x over previous
//
#include <hip/hip_runtime.h>

#define EPSV 1e-5f
#define CLS_SZ (32768*6)
#define FWS_FLOATS ((size_t)196608 * 128)

// 128-row layout (mono fallback only)
#define AL(ch,row) (((ch)<<7) + ((row) ^ ((((ch)&15))<<3)))
// 64-row layout: [ch][row], 8-row-group XOR swizzle
#define AL64(ch,row) (((ch)<<6) + ((row) ^ ((((ch)&7))<<3)))

__device__ __forceinline__ float4 ld4(const float* p) { return *reinterpret_cast<const float4*>(p); }
__device__ __forceinline__ void st4(float* p, float4 v) { *reinterpret_cast<float4*>(p) = v; }

// ---------------- W register streaming (shared) ----------------
__device__ __forceinline__ void ldW2(const float* __restrict__ Wg, int k0, int jg4,
                                     float4 (&w0)[2], float4 (&w1)[2])
{
  #pragma unroll
  for (int kk = 0; kk < 2; ++kk) {
    w0[kk] = ld4(Wg + (k0 + kk)*128 + jg4);
    w1[kk] = ld4(Wg + (k0 + kk)*128 + 64 + jg4);
  }
}

// ---------------- 64-row gemm: 4 rows x 8 cols per thread ----------------
__device__ __forceinline__ void fma2_64(const float* X, int k0, int ag,
                                        const float4 (&w0)[2], const float4 (&w1)[2],
                                        float (&acc)[4][8])
{
  #pragma unroll
  for (int kk = 0; kk < 2; ++kk) {
    int k = k0 + kk;
    float4 x = ld4(X + (k<<6) + ((ag<<2) ^ ((k & 7)<<3)));
    float xv[4] = {x.x,x.y,x.z,x.w};
    float wv[8] = {w0[kk].x,w0[kk].y,w0[kk].z,w0[kk].w,
                   w1[kk].x,w1[kk].y,w1[kk].z,w1[kk].w};
    #pragma unroll
    for (int r = 0; r < 4; ++r)
      #pragma unroll
      for (int c2 = 0; c2 < 8; ++c2)
        acc[r][c2] = fmaf(xv[r], wv[c2], acc[r][c2]);
  }
}

__device__ __forceinline__ void gemmR64(const float* X, const float* __restrict__ Wg,
                                        float (&acc)[4][8], int ag, int jg4)
{
  float4 a0[2], a1[2], b0[2], b1[2];
  ldW2(Wg, 0, jg4, a0, a1);
  #pragma unroll 1
  for (int c = 0; c < 64; c += 2) {
    ldW2(Wg, (c+1)*2, jg4, b0, b1);
    fma2_64(X, c*2, ag, a0, a1, acc);
    if (c + 2 < 64) ldW2(Wg, (c+2)*2, jg4, a0, a1);
    fma2_64(X, (c+1)*2, ag, b0, b1, acc);
  }
}

// output-layer (pred L3): W [128][60]; cols jg*4..+3 (jg<15)
__device__ __forceinline__ void ldWo(const float* __restrict__ Wg, int k0, int jg,
                                     bool ldw, float4 (&w)[8])
{
  #pragma unroll
  for (int kk = 0; kk < 8; ++kk)
    w[kk] = ldw ? ld4(Wg + (k0 + kk)*60 + jg*4) : make_float4(0.f,0.f,0.f,0.f);
}

__device__ __forceinline__ void fmaWo64(const float* X, int k0, int ag,
                                        const float4 (&w)[8], float (&acc)[4][4])
{
  #pragma unroll
  for (int kk = 0; kk < 8; ++kk) {
    int k = k0 + kk;
    float4 x = ld4(X + (k<<6) + ((ag<<2) ^ ((k & 7)<<3)));
    float xv[4] = {x.x,x.y,x.z,x.w};
    float wv[4] = {w[kk].x,w[kk].y,w[kk].z,w[kk].w};
    #pragma unroll
    for (int r = 0; r < 4; ++r)
      #pragma unroll
      for (int c2 = 0; c2 < 4; ++c2)
        acc[r][c2] = fmaf(xv[r], wv[c2], acc[r][c2]);
  }
}

__device__ __forceinline__ void gemmWoR64(const float* X, const float* __restrict__ Wg,
                                          float (&acc)[4][4], int ag, int jg)
{
  const bool ldw = (jg < 15);
  float4 a[8], b[8];
  ldWo(Wg, 0, jg, ldw, a);
  #pragma unroll 1
  for (int c = 0; c < 16; c += 2) {
    ldWo(Wg, (c+1)*8, jg, ldw, b);
    fmaWo64(X, c*8, ag, a, acc);
    if (c + 2 < 16) ldWo(Wg, (c+2)*8, jg, ldw, a);
    fmaWo64(X, (c+1)*8, ag, b, acc);
  }
}

// ---------------- GroupNorm stats (64-row) — R3's exact value tree ----------------
__device__ __forceinline__ void gn_finish64(float* PS1, float* PS2, float* MEAN, float* RSTD, int tid)
{
  __syncthreads();
  if (tid < 64) {
    float a = 0.f, b = 0.f;
    #pragma unroll
    for (int j = 0; j < 4; ++j) { a += PS1[tid*4 + j]; b += PS2[tid*4 + j]; }
    float mu = a * 0.0078125f;
    float var = b * 0.0078125f - mu*mu;
    MEAN[tid] = mu;
    RSTD[tid] = rsqrtf(var + EPSV);
  }
  __syncthreads();
}

__device__ __forceinline__ void gn_reduce4_64(const float (&acc)[4][8], float* PS1, float* PS2,
                                              float* MEAN, float* RSTD, int ag, int jg, int tid)
{
  #pragma unroll
  for (int r = 0; r < 4; ++r) {
    float s = 0.f, q = 0.f;
    #pragma unroll
    for (int c = 0; c < 8; ++c) { float v = acc[r][c]; s += v; q += v*v; }
    s += __shfl_xor(s, 1, 64); q += __shfl_xor(q, 1, 64);
    s += __shfl_xor(s, 2, 64); q += __shfl_xor(q, 2, 64);
    if ((jg & 3) == 0) { int row = ag*4 + r; PS1[row*4 + (jg>>2)] = s; PS2[row*4 + (jg>>2)] = q; }
  }
  gn_finish64(PS1, PS2, MEAN, RSTD, tid);
}

// ---------------- Kernel A: per-mode pred heads -> unsorted reg ----------------
// LDS: 32768 + 2048 + 512 = 35328 B; VGPR<=128 -> 4 blocks/CU
__global__ void __launch_bounds__(256, 2) pred_kernel(
    const float* __restrict__ actors, const float* __restrict__ ctrs,
    const float* __restrict__ W1, const float* __restrict__ g1v, const float* __restrict__ b1v,
    const float* __restrict__ W2, const float* __restrict__ g2v, const float* __restrict__ b2v,
    const float* __restrict__ Wo, const float* __restrict__ bov,
    float* __restrict__ out_reg)
{
  __shared__ __align__(16) float ACT[8192];
  __shared__ float PS1[256], PS2[256], MEAN[64], RSTD[64];

  const int tid = threadIdx.x;
  const int jg = tid & 15, ag = tid >> 4;   // rows ag*4..+3, ag in 0..15
  const int jg4 = jg*4;
  const int m  = blockIdx.y;
  const int n0 = blockIdx.x * 64;

  // stage actors tile: row-per-lane (LDS conflict-free; global gathers hit L1/L2)
  #pragma unroll
  for (int p = 0; p < 8; ++p) {
    int i = (p<<8) + tid;
    int r = i & 63, ch0 = (i >> 6) << 2;
    float4 v = ld4(actors + (size_t)(n0 + r)*128 + ch0);
    ACT[AL64(ch0+0, r)] = v.x; ACT[AL64(ch0+1, r)] = v.y;
    ACT[AL64(ch0+2, r)] = v.z; ACT[AL64(ch0+3, r)] = v.w;
  }
  __syncthreads();

  float acc[4][8];
  #pragma unroll
  for (int r = 0; r < 4; ++r)
    #pragma unroll
    for (int c = 0; c < 8; ++c) acc[r][c] = 0.f;

  // L1: relu(GN(actors @ W1)) -> ACT
  gemmR64(ACT, W1 + (size_t)m*16384, acc, ag, jg4);
  gn_reduce4_64(acc, PS1, PS2, MEAN, RSTD, ag, jg, tid);
  {
    float mu[4], rs[4];
    #pragma unroll
    for (int r = 0; r < 4; ++r) { mu[r] = MEAN[ag*4+r]; rs[r] = RSTD[ag*4+r]; }
    float4 gl = ld4(g1v + m*128 + jg4), gh = ld4(g1v + m*128 + 64 + jg4);
    float4 bl = ld4(b1v + m*128 + jg4), bh = ld4(b1v + m*128 + 64 + jg4);
    float gv[8] = {gl.x,gl.y,gl.z,gl.w,gh.x,gh.y,gh.z,gh.w};
    float bv[8] = {bl.x,bl.y,bl.z,bl.w,bh.x,bh.y,bh.z,bh.w};
    float vm[4][8];
    #pragma unroll
    for (int r = 0; r < 4; ++r)
      #pragma unroll
      for (int c = 0; c < 8; ++c)
        vm[r][c] = fmaxf((acc[r][c] - mu[r]) * rs[r] * gv[c] + bv[c], 0.f);
    #pragma unroll
    for (int c = 0; c < 8; ++c) {
      int ch = (c < 4) ? (jg4 + c) : (64 + jg4 + (c - 4));
      st4(ACT + AL64(ch, ag*4), make_float4(vm[0][c],vm[1][c],vm[2][c],vm[3][c]));
    }
  }
  __syncthreads();

  #pragma unroll
  for (int r = 0; r < 4; ++r)
    #pragma unroll
    for (int c = 0; c < 8; ++c) acc[r][c] = 0.f;

  // L2: relu(GN(h1 @ W2) + actors) -> ACT
  gemmR64(ACT, W2 + (size_t)m*16384, acc, ag, jg4);
  gn_reduce4_64(acc, PS1, PS2, MEAN, RSTD, ag, jg, tid);
  {
    float mu[4], rs[4];
    #pragma unroll
    for (int r = 0; r < 4; ++r) { mu[r] = MEAN[ag*4+r]; rs[r] = RSTD[ag*4+r]; }
    float4 gl = ld4(g2v + m*128 + jg4), gh = ld4(g2v + m*128 + 64 + jg4);
    float4 bl = ld4(b2v + m*128 + jg4), bh = ld4(b2v + m*128 + 64 + jg4);
    float gv[8] = {gl.x,gl.y,gl.z,gl.w,gh.x,gh.y,gh.z,gh.w};
    float bv[8] = {bl.x,bl.y,bl.z,bl.w,bh.x,bh.y,bh.z,bh.w};
    float vm[4][8];
    #pragma unroll
    for (int r = 0; r < 4; ++r) {
      const float* ap = actors + (size_t)(n0 + ag*4 + r)*128;
      float4 a0 = ld4(ap + jg4), a1 = ld4(ap + 64 + jg4);
      float av[8] = {a0.x,a0.y,a0.z,a0.w,a1.x,a1.y,a1.z,a1.w};
      #pragma unroll
      for (int c = 0; c < 8; ++c)
        vm[r][c] = fmaxf((acc[r][c] - mu[r]) * rs[r] * gv[c] + bv[c] + av[c], 0.f);
    }
    #pragma unroll
    for (int c = 0; c < 8; ++c) {
      int ch = (c < 4) ? (jg4 + c) : (64 + jg4 + (c - 4));
      st4(ACT + AL64(ch, ag*4), make_float4(vm[0][c],vm[1][c],vm[2][c],vm[3][c]));
    }
  }
  __syncthreads();

  // L3: h @ Wo + bo + ctr -> reg
  float acc2[4][4];
  #pragma unroll
  for (int r = 0; r < 4; ++r)
    #pragma unroll
    for (int c = 0; c < 4; ++c) acc2[r][c] = 0.f;
  gemmWoR64(ACT, Wo + (size_t)m*7680, acc2, ag, jg);

  if (jg < 15) {
    float4 bo4 = ld4(bov + m*60 + jg4);
    #pragma unroll
    for (int r = 0; r < 4; ++r) {
      int n = n0 + ag*4 + r;
      float2 cc = *reinterpret_cast<const float2*>(ctrs + 2*n);
      float4 v;
      v.x = acc2[r][0] + bo4.x + cc.x;
      v.y = acc2[r][1] + bo4.y + cc.y;
      v.z = acc2[r][2] + bo4.z + cc.x;
      v.w = acc2[r][3] + bo4.w + cc.y;
      st4(out_reg + (size_t)n*360 + m*60 + jg4, v);
    }
  }
}

// ---------------- Kernel B1: AttDest -> feats (to workspace) ----------------
__global__ void __launch_bounds__(256, 2) att_feats_kernel(
    const float* __restrict__ actors, const float* __restrict__ ctrs,
    const float* __restrict__ dW1, const float* __restrict__ db1,
    const float* __restrict__ dW2, const float* __restrict__ dg2, const float* __restrict__ db2,
    const float* __restrict__ aW, const float* __restrict__ aG, const float* __restrict__ aB,
    const float* __restrict__ reg, float* __restrict__ fws)
{
  __shared__ __align__(16) float ACT[8192];
  __shared__ float PS1[256], PS2[256], MEAN[64], RSTD[64];
  float* D0x = MEAN;   // lifetimes disjoint (consumed in P1; MEAN written in P2 gn)
  float* D0y = RSTD;

  const int tid = threadIdx.x;
  const int jg = tid & 15, ag = tid >> 4;
  const int jg4 = jg*4;
  const int r0 = blockIdx.x * 64;

  // P0: dist0 = ctr - reg_last
  if (tid < 64) {
    int rg = r0 + tid;
    int n = rg / 6, mm = rg - 6*n;
    size_t base = (size_t)n*360 + mm*60;
    float2 c2 = *reinterpret_cast<const float2*>(ctrs + 2*n);
    D0x[tid] = c2.x - reg[base + 58];
    D0y[tid] = c2.y - reg[base + 59];
  }
  __syncthreads();

  // P1: dist1 = relu(dist0 @ dW1 + db1) -> ACT
  {
    float dx[4], dy[4];
    #pragma unroll
    for (int r = 0; r < 4; ++r) { dx[r] = D0x[ag*4+r]; dy[r] = D0y[ag*4+r]; }
    #pragma unroll
    for (int c = 0; c < 8; ++c) {
      int ch = (c < 4) ? (jg4 + c) : (64 + jg4 + (c - 4));
      float w1 = dW1[ch], w2 = dW1[128 + ch], bb = db1[ch];
      float4 v;
      v.x = fmaxf(fmaf(dx[0], w1, fmaf(dy[0], w2, bb)), 0.f);
      v.y = fmaxf(fmaf(dx[1], w1, fmaf(dy[1], w2, bb)), 0.f);
      v.z = fmaxf(fmaf(dx[2], w1, fmaf(dy[2], w2, bb)), 0.f);
      v.w = fmaxf(fmaf(dx[3], w1, fmaf(dy[3], w2, bb)), 0.f);
      st4(ACT + AL64(ch, ag*4), v);
    }
  }
  __syncthreads();

  float acc[4][8];
  #pragma unroll
  for (int r = 0; r < 4; ++r)
    #pragma unroll
    for (int c = 0; c < 8; ++c) acc[r][c] = 0.f;

  // P2: dist2 = relu(GN(dist1 @ dW2)) -> ACT
  gemmR64(ACT, dW2, acc, ag, jg4);
  gn_reduce4_64(acc, PS1, PS2, MEAN, RSTD, ag, jg, tid);
  {
    float mu[4], rs[4];
    #pragma unroll
    for (int r = 0; r < 4; ++r) { mu[r] = MEAN[ag*4+r]; rs[r] = RSTD[ag*4+r]; }
    float4 gl = ld4(dg2 + jg4), gh = ld4(dg2 + 64 + jg4);
    float4 bl = ld4(db2 + jg4), bh = ld4(db2 + 64 + jg4);
    float gv[8] = {gl.x,gl.y,gl.z,gl.w,gh.x,gh.y,gh.z,gh.w};
    float bv[8] = {bl.x,bl.y,bl.z,bl.w,bh.x,bh.y,bh.z,bh.w};
    float vm[4][8];
    #pragma unroll
    for (int r = 0; r < 4; ++r)
      #pragma unroll
      for (int c = 0; c < 8; ++c)
        vm[r][c] = fmaxf((acc[r][c] - mu[r]) * rs[r] * gv[c] + bv[c], 0.f);
    #pragma unroll
    for (int c = 0; c < 8; ++c) {
      int ch = (c < 4) ? (jg4 + c) : (64 + jg4 + (c - 4));
      st4(ACT + AL64(ch, ag*4), make_float4(vm[0][c],vm[1][c],vm[2][c],vm[3][c]));
    }
  }
  __syncthreads();

  // P3: feats = relu(GN(dist2 @ aW_lo + agts @ aW_hi)) -> fws
  #pragma unroll
  for (int r = 0; r < 4; ++r)
    #pragma unroll
    for (int c = 0; c < 8; ++c) acc[r][c] = 0.f;
  gemmR64(ACT, aW, acc, ag, jg4);
  __syncthreads();                 // all waves done reading dist2
  #pragma unroll
  for (int p = 0; p < 8; ++p) {
    int i = (p<<8) + tid;
    int r = i & 63, ch0 = (i >> 6) << 2;
    int n = (r0 + r) / 6;
    float4 v = ld4(actors + (size_t)n*128 + ch0);
    ACT[AL64(ch0+0, r)] = v.x; ACT[AL64(ch0+1, r)] = v.y;
    ACT[AL64(ch0+2, r)] = v.z; ACT[AL64(ch0+3, r)] = v.w;
  }
  __syncthreads();                 // agts staged
  gemmR64(ACT, aW + 16384, acc, ag, jg4);
  gn_reduce4_64(acc, PS1, PS2, MEAN, RSTD, ag, jg, tid);
  {
    float mu[4], rs[4];
    #pragma unroll
    for (int r = 0; r < 4; ++r) { mu[r] = MEAN[ag*4+r]; rs[r] = RSTD[ag*4+r]; }
    float4 gl = ld4(aG + jg4), gh = ld4(aG + 64 + jg4);
    float4 bl = ld4(aB + jg4), bh = ld4(aB + 64 + jg4);
    float gv[8] = {gl.x,gl.y,gl.z,gl.w,gh.x,gh.y,gh.z,gh.w};
    float bv[8] = {bl.x,bl.y,bl.z,bl.w,bh.x,bh.y,bh.z,bh.w};
    #pragma unroll
    for (int r = 0; r < 4; ++r) {
      float fv[8];
      #pragma unroll
      for (int c = 0; c < 8; ++c)
        fv[c] = fmaxf((acc[r][c] - mu[r]) * rs[r] * gv[c] + bv[c], 0.f);
      float* fp = fws + (size_t)(r0 + ag*4 + r)*128;
      st4(fp + jg4,      make_float4(fv[0],fv[1],fv[2],fv[3]));
      st4(fp + 64 + jg4, make_float4(fv[4],fv[5],fv[6],fv[7]));
    }
  }
}

// ---------------- Kernel B2: cls head from feats(ws) -> unsorted cls ----------------
__global__ void __launch_bounds__(256, 2) att_cls2_kernel(
    const float* __restrict__ cW1, const float* __restrict__ cg1, const float* __restrict__ cb1,
    const float* __restrict__ cW2, const float* __restrict__ cg2, const float* __restrict__ cb2,
    const float* __restrict__ cWo, const float* __restrict__ cbo,
    const float* __restrict__ fws, float* __restrict__ cls_out)
{
  __shared__ __align__(16) float ACT[8192];
  __shared__ float PS1[256], PS2[256], MEAN[64], RSTD[64];

  const int tid = threadIdx.x;
  const int jg = tid & 15, ag = tid >> 4;
  const int jg4 = jg*4;
  const int r0 = blockIdx.x * 64;

  #pragma unroll
  for (int p = 0; p < 8; ++p) {
    int i = (p<<8) + tid;
    int r = i & 63, ch0 = (i >> 6) << 2;
    float4 v = ld4(fws + (size_t)(r0 + r)*128 + ch0);
    ACT[AL64(ch0+0, r)] = v.x; ACT[AL64(ch0+1, r)] = v.y;
    ACT[AL64(ch0+2, r)] = v.z; ACT[AL64(ch0+3, r)] = v.w;
  }
  __syncthreads();

  float acc[4][8];
  #pragma unroll
  for (int r = 0; r < 4; ++r)
    #pragma unroll
    for (int c = 0; c < 8; ++c) acc[r][c] = 0.f;

  // P4: c1 = relu(GN(feats @ cls_W1)) -> ACT
  gemmR64(ACT, cW1, acc, ag, jg4);
  gn_reduce4_64(acc, PS1, PS2, MEAN, RSTD, ag, jg, tid);
  {
    float mu[4], rs[4];
    #pragma unroll
    for (int r = 0; r < 4; ++r) { mu[r] = MEAN[ag*4+r]; rs[r] = RSTD[ag*4+r]; }
    float4 gl = ld4(cg1 + jg4), gh = ld4(cg1 + 64 + jg4);
    float4 bl = ld4(cb1 + jg4), bh = ld4(cb1 + 64 + jg4);
    float gv[8] = {gl.x,gl.y,gl.z,gl.w,gh.x,gh.y,gh.z,gh.w};
    float bv[8] = {bl.x,bl.y,bl.z,bl.w,bh.x,bh.y,bh.z,bh.w};
    float vm[4][8];
    #pragma unroll
    for (int r = 0; r < 4; ++r)
      #pragma unroll
      for (int c = 0; c < 8; ++c)
        vm[r][c] = fmaxf((acc[r][c] - mu[r]) * rs[r] * gv[c] + bv[c], 0.f);
    #pragma unroll
    for (int c = 0; c < 8; ++c) {
      int ch = (c < 4) ? (jg4 + c) : (64 + jg4 + (c - 4));
      st4(ACT + AL64(ch, ag*4), make_float4(vm[0][c],vm[1][c],vm[2][c],vm[3][c]));
    }
  }
  __syncthreads();

  // P5: c2 = GN(c1 @ cls_W2); c = relu(c2 + feats); cls = c @ cls_Wo + bo
  #pragma unroll
  for (int r = 0; r < 4; ++r)
    #pragma unroll
    for (int c = 0; c < 8; ++c) acc[r][c] = 0.f;
  gemmR64(ACT, cW2, acc, ag, jg4);
  gn_reduce4_64(acc, PS1, PS2, MEAN, RSTD, ag, jg, tid);
  {
    float mu[4], rs[4];
    #pragma unroll
    for (int r = 0; r < 4; ++r) { mu[r] = MEAN[ag*4+r]; rs[r] = RSTD[ag*4+r]; }
    float4 gl = ld4(cg2 + jg4), gh = ld4(cg2 + 64 + jg4);
    float4 bl = ld4(cb2 + jg4), bh = ld4(cb2 + 64 + jg4);
    float4 wl = ld4(cWo + jg4), wh = ld4(cWo + 64 + jg4);
    float gv[8] = {gl.x,gl.y,gl.z,gl.w,gh.x,gh.y,gh.z,gh.w};
    float bv[8] = {bl.x,bl.y,bl.z,bl.w,bh.x,bh.y,bh.z,bh.w};
    float wv[8] = {wl.x,wl.y,wl.z,wl.w,wh.x,wh.y,wh.z,wh.w};
    #pragma unroll
    for (int r = 0; r < 4; ++r) {
      const float* fp = fws + (size_t)(r0 + ag*4 + r)*128;
      float4 a0 = ld4(fp + jg4), a1 = ld4(fp + 64 + jg4);
      float av[8] = {a0.x,a0.y,a0.z,a0.w,a1.x,a1.y,a1.z,a1.w};
      float p = 0.f;
      #pragma unroll
      for (int c = 0; c < 8; ++c) {
        float v = (acc[r][c] - mu[r]) * rs[r] * gv[c] + bv[c];
        v = fmaxf(v + av[c], 0.f);
        p = fmaf(v, wv[c], p);
      }
      float s = p;
      s += __shfl_xor(s, 1, 64);
      s += __shfl_xor(s, 2, 64);
      if ((jg & 3) == 0) PS1[(ag*4+r)*4 + (jg>>2)] = s;
    }
  }
  __syncthreads();
  if (tid < 64) {
    float s = 0.f;
    #pragma unroll
    for (int j = 0; j < 4; ++j) s += PS1[tid*4 + j];
    cls_out[r0 + tid] = s + cbo[0];
  }
}

// ---------------- Fallback: monolithic att (128-row gemmR), if ws too small ----------------
__device__ __forceinline__ void fma2(const float* X, int k0, int ag,
                                     const float4 (&w0)[2], const float4 (&w1)[2],
                                     float (&acc)[8][8])
{
  #pragma unroll
  for (int kk = 0; kk < 2; ++kk) {
    int k = k0 + kk;
    const float* xp = X + (k<<7) + ((ag<<3) ^ ((k & 15)<<3));
    float4 x0 = ld4(xp), x1 = ld4(xp + 4);
    float xv[8] = {x0.x,x0.y,x0.z,x0.w,x1.x,x1.y,x1.z,x1.w};
    float wv[8] = {w0[kk].x,w0[kk].y,w0[kk].z,w0[kk].w,
                   w1[kk].x,w1[kk].y,w1[kk].z,w1[kk].w};
    #pragma unroll
    for (int r = 0; r < 8; ++r)
      #pragma unroll
      for (int c2 = 0; c2 < 8; ++c2)
        acc[r][c2] = fmaf(xv[r], wv[c2], acc[r][c2]);
  }
}

__device__ __forceinline__ void gemmR(const float* X, const float* __restrict__ Wg,
                                      float (&acc)[8][8], int ag, int jg4)
{
  float4 a0[2], a1[2], b0[2], b1[2];
  ldW2(Wg, 0, jg4, a0, a1);
  #pragma unroll 1
  for (int c = 0; c < 64; c += 2) {
    ldW2(Wg, (c+1)*2, jg4, b0, b1);
    fma2(X, c*2, ag, a0, a1, acc);
    if (c + 2 < 64) ldW2(Wg, (c+2)*2, jg4, a0, a1);
    fma2(X, (c+1)*2, ag, b0, b1, acc);
  }
}

__device__ __forceinline__ void gn_finish128(float* PS1, float* PS2, float* MEAN, float* RSTD, int tid)
{
  __syncthreads();
  if (tid < 128) {
    float a = 0.f, b = 0.f;
    #pragma unroll
    for (int j = 0; j < 4; ++j) { a += PS1[tid*4 + j]; b += PS2[tid*4 + j]; }
    float mu = a * 0.0078125f;
    float var = b * 0.0078125f - mu*mu;
    MEAN[tid] = mu;
    RSTD[tid] = rsqrtf(var + EPSV);
  }
  __syncthreads();
}

__device__ __forceinline__ void gn_reduce8(const float (&acc)[8][8], float* PS1, float* PS2,
                                           float* MEAN, float* RSTD, int ag, int jg, int tid)
{
  #pragma unroll
  for (int r = 0; r < 8; ++r) {
    float s = 0.f, q = 0.f;
    #pragma unroll
    for (int c = 0; c < 8; ++c) { float v = acc[r][c]; s += v; q += v*v; }
    s += __shfl_xor(s, 1, 64); q += __shfl_xor(q, 1, 64);
    s += __shfl_xor(s, 2, 64); q += __shfl_xor(q, 2, 64);
    if ((jg & 3) == 0) { int row = ag*8 + r; PS1[row*4 + (jg>>2)] = s; PS2[row*4 + (jg>>2)] = q; }
  }
  gn_finish128(PS1, PS2, MEAN, RSTD, tid);
}

__global__ void __launch_bounds__(256, 2) att_cls_mono_kernel(
    const float* __restrict__ actors, const float* __restrict__ ctrs,
    const float* __restrict__ dW1, const float* __restrict__ db1,
    const float* __restrict__ dW2, const float* __restrict__ dg2, const float* __restrict__ db2,
    const float* __restrict__ aW, const float* __restrict__ aG, const float* __restrict__ aB,
    const float* __restrict__ cW1, const float* __restrict__ cg1, const float* __restrict__ cb1,
    const float* __restrict__ cW2, const float* __restrict__ cg2, const float* __restrict__ cb2,
    const float* __restrict__ cWo, const float* __restrict__ cbo,
    const float* __restrict__ reg, float* __restrict__ cls_out)
{
  __shared__ __align__(16) float ACT[16384];
  __shared__ float PS1[512], PS2[512], MEAN[128], RSTD[128];
  float* D0x = MEAN;
  float* D0y = RSTD;

  const int tid = threadIdx.x;
  const int jg = tid & 15, ag = tid >> 4;
  const int jg4 = jg*4;
  const int r0 = blockIdx.x * 128;

  if (tid < 128) {
    int rg = r0 + tid;
    int n = rg / 6, mm = rg - 6*n;
    size_t base = (size_t)n*360 + mm*60;
    float2 c2 = *reinterpret_cast<const float2*>(ctrs + 2*n);
    D0x[tid] = c2.x - reg[base + 58];
    D0y[tid] = c2.y - reg[base + 59];
  }
  __syncthreads();

  {
    float dx[8], dy[8];
    #pragma unroll
    for (int r = 0; r < 8; ++r) { dx[r] = D0x[ag*8+r]; dy[r] = D0y[ag*8+r]; }
    #pragma unroll
    for (int c = 0; c < 8; ++c) {
      int ch = (c < 4) ? (jg4 + c) : (64 + jg4 + (c - 4));
      float w1 = dW1[ch], w2 = dW1[128 + ch], bb = db1[ch];
      float v[8];
      #pragma unroll
      for (int r = 0; r < 8; ++r) v[r] = fmaxf(fmaf(dx[r], w1, fmaf(dy[r], w2, bb)), 0.f);
      int base = (ch<<7) + ((ag<<3) ^ ((ch & 15)<<3));
      st4(ACT + base,     make_float4(v[0],v[1],v[2],v[3]));
      st4(ACT + base + 4, make_float4(v[4],v[5],v[6],v[7]));
    }
  }
  __syncthreads();

  float acc[8][8];
  #pragma unroll
  for (int r = 0; r < 8; ++r)
    #pragma unroll
    for (int c = 0; c < 8; ++c) acc[r][c] = 0.f;

  gemmR(ACT, dW2, acc, ag, jg4);
  gn_reduce8(acc, PS1, PS2, MEAN, RSTD, ag, jg, tid);
  {
    float mu[8], rs[8];
    #pragma unroll
    for (int r = 0; r < 8; ++r) { mu[r] = MEAN[ag*8+r]; rs[r] = RSTD[ag*8+r]; }
    float4 gl = ld4(dg2 + jg4), gh = ld4(dg2 + 64 + jg4);
    float4 bl = ld4(db2 + jg4), bh = ld4(db2 + 64 + jg4);
    float gv[8] = {gl.x,gl.y,gl.z,gl.w,gh.x,gh.y,gh.z,gh.w};
    float bv[8] = {bl.x,bl.y,bl.z,bl.w,bh.x,bh.y,bh.z,bh.w};
    float vm[8][8];
    #pragma unroll
    for (int r = 0; r < 8; ++r)
      #pragma unroll
      for (int c = 0; c < 8; ++c)
        vm[r][c] = fmaxf((acc[r][c] - mu[r]) * rs[r] * gv[c] + bv[c], 0.f);
    #pragma unroll
    for (int c = 0; c < 8; ++c) {
      int ch = (c < 4) ? (jg4 + c) : (64 + jg4 + (c - 4));
      int base = (ch<<7) + ((ag<<3) ^ ((ch & 15)<<3));
      st4(ACT + base,     make_float4(vm[0][c],vm[1][c],vm[2][c],vm[3][c]));
      st4(ACT + base + 4, make_float4(vm[4][c],vm[5][c],vm[6][c],vm[7][c]));
    }
  }
  __syncthreads();

  #pragma unroll
  for (int r = 0; r < 8; ++r)
    #pragma unroll
    for (int c = 0; c < 8; ++c) acc[r][c] = 0.f;
  gemmR(ACT, aW, acc, ag, jg4);
  __syncthreads();
  #pragma unroll
  for (int p = 0; p < 16; ++p) {
    int i = (p<<8) + tid;
    int r = i >> 5, q4 = (i & 31) << 2;
    int n = (r0 + r) / 6;
    float4 v = ld4(actors + (size_t)n*128 + q4);
    ACT[AL(q4+0, r)] = v.x; ACT[AL(q4+1, r)] = v.y;
    ACT[AL(q4+2, r)] = v.z; ACT[AL(q4+3, r)] = v.w;
  }
  __syncthreads();
  gemmR(ACT, aW + 16384, acc, ag, jg4);
  gn_reduce8(acc, PS1, PS2, MEAN, RSTD, ag, jg, tid);
  float feats[8][8];
  {
    float mu[8], rs[8];
    #pragma unroll
    for (int r = 0; r < 8; ++r) { mu[r] = MEAN[ag*8+r]; rs[r] = RSTD[ag*8+r]; }
    float4 gl = ld4(aG + jg4), gh = ld4(aG + 64 + jg4);
    float4 bl = ld4(aB + jg4), bh = ld4(aB + 64 + jg4);
    float gv[8] = {gl.x,gl.y,gl.z,gl.w,gh.x,gh.y,gh.z,gh.w};
    float bv[8] = {bl.x,bl.y,bl.z,bl.w,bh.x,bh.y,bh.z,bh.w};
    #pragma unroll
    for (int r = 0; r < 8; ++r)
      #pragma unroll
      for (int c = 0; c < 8; ++c)
        feats[r][c] = fmaxf((acc[r][c] - mu[r]) * rs[r] * gv[c] + bv[c], 0.f);
    #pragma unroll
    for (int c = 0; c < 8; ++c) {
      int ch = (c < 4) ? (jg4 + c) : (64 + jg4 + (c - 4));
      int base = (ch<<7) + ((ag<<3) ^ ((ch & 15)<<3));
      st4(ACT + base,     make_float4(feats[0][c],feats[1][c],feats[2][c],feats[3][c]));
      st4(ACT + base + 4, make_float4(feats[4][c],feats[5][c],feats[6][c],feats[7][c]));
    }
  }
  __syncthreads();

  #pragma unroll
  for (int r = 0; r < 8; ++r)
    #pragma unroll
    for (int c = 0; c < 8; ++c) acc[r][c] = 0.f;
  gemmR(ACT, cW1, acc, ag, jg4);
  gn_reduce8(acc, PS1, PS2, MEAN, RSTD, ag, jg, tid);
  {
    float mu[8], rs[8];
    #pragma unroll
    for (int r = 0; r < 8; ++r) { mu[r] = MEAN[ag*8+r]; rs[r] = RSTD[ag*8+r]; }
    float4 gl = ld4(cg1 + jg4), gh = ld4(cg1 + 64 + jg4);
    float4 bl = ld4(cb1 + jg4), bh = ld4(cb1 + 64 + jg4);
    float gv[8] = {gl.x,gl.y,gl.z,gl.w,gh.x,gh.y,gh.z,gh.w};
    float bv[8] = {bl.x,bl.y,bl.z,bl.w,bh.x,bh.y,bh.z,bh.w};
    float vm[8][8];
    #pragma unroll
    for (int r = 0; r < 8; ++r)
      #pragma unroll
      for (int c = 0; c < 8; ++c)
        vm[r][c] = fmaxf((acc[r][c] - mu[r]) * rs[r] * gv[c] + bv[c], 0.f);
    #pragma unroll
    for (int c = 0; c < 8; ++c) {
      int ch = (c < 4) ? (jg4 + c) : (64 + jg4 + (c - 4));
      int base = (ch<<7) + ((ag<<3) ^ ((ch & 15)<<3));
      st4(ACT + base,     make_float4(vm[0][c],vm[1][c],vm[2][c],vm[3][c]));
      st4(ACT + base + 4, make_float4(vm[4][c],vm[5][c],vm[6][c],vm[7][c]));
    }
  }
  __syncthreads();

  #pragma unroll
  for (int r = 0; r < 8; ++r)
    #pragma unroll
    for (int c = 0; c < 8; ++c) acc[r][c] = 0.f;
  gemmR(ACT, cW2, acc, ag, jg4);
  gn_reduce8(acc, PS1, PS2, MEAN, RSTD, ag, jg, tid);
  {
    float mu[8], rs[8], p[8];
    #pragma unroll
    for (int r = 0; r < 8; ++r) { mu[r] = MEAN[ag*8+r]; rs[r] = RSTD[ag*8+r]; p[r] = 0.f; }
    float4 gl = ld4(cg2 + jg4), gh = ld4(cg2 + 64 + jg4);
    float4 bl = ld4(cb2 + jg4), bh = ld4(cb2 + 64 + jg4);
    float4 wl = ld4(cWo + jg4), wh = ld4(cWo + 64 + jg4);
    float gv[8] = {gl.x,gl.y,gl.z,gl.w,gh.x,gh.y,gh.z,gh.w};
    float bv[8] = {bl.x,bl.y,bl.z,bl.w,bh.x,bh.y,bh.z,bh.w};
    float wv[8] = {wl.x,wl.y,wl.z,wl.w,wh.x,wh.y,wh.z,wh.w};
    #pragma unroll
    for (int c = 0; c < 8; ++c) {
      #pragma unroll
      for (int r = 0; r < 8; ++r) {
        float v = (acc[r][c] - mu[r]) * rs[r] * gv[c] + bv[c];
        v = fmaxf(v + feats[r][c], 0.f);
        p[r] = fmaf(v, wv[c], p[r]);
      }
    }
    #pragma unroll
    for (int r = 0; r < 8; ++r) {
      float s = p[r];
      s += __shfl_xor(s, 1, 64);
      s += __shfl_xor(s, 2, 64);
      if ((jg & 3) == 0) PS1[(ag*8+r)*4 + (jg>>2)] = s;
    }
  }
  __syncthreads();
  if (tid < 128) {
    float s = 0.f;
    #pragma unroll
    for (int j = 0; j < 4; ++j) s += PS1[tid*4 + j];
    cls_out[r0 + tid] = s + cbo[0];
  }
}

// ---------------- Kernel C: per-actor stable descending sort + permute ----------------
__global__ void __launch_bounds__(256) sort_kernel(float* __restrict__ out)
{
  __shared__ float RL[64*360];
  __shared__ float CL[64*6];
  __shared__ float CS[64*6];
  __shared__ int   ORD[64*6];

  const int tid = threadIdx.x;
  const int n0 = blockIdx.x * 64;
  float* regp = out + CLS_SZ;

  for (int i = tid; i < 64*360; i += 256) RL[i] = regp[(size_t)n0*360 + i];
  for (int i = tid; i < 384; i += 256)    CL[i] = out[n0*6 + i];
  __syncthreads();

  if (tid < 64) {
    float v[6];
    #pragma unroll
    for (int m2 = 0; m2 < 6; ++m2) v[m2] = CL[tid*6 + m2];
    int used = 0;
    for (int j = 0; j < 6; ++j) {
      int best = -1; float bv = 0.f;
      for (int m2 = 0; m2 < 6; ++m2) {
        if (used & (1 << m2)) continue;
        if (best < 0 || v[m2] > bv) { best = m2; bv = v[m2]; }  // stable: strict >
      }
      used |= (1 << best);
      ORD[tid*6 + j] = best;
      CS[tid*6 + j] = bv;
    }
  }
  __syncthreads();

  for (int i = tid; i < 384; i += 256) out[n0*6 + i] = CS[i];
  for (int i = tid; i < 64*360; i += 256) {
    int rl = i / 360, rem = i - rl*360;
    int slot = rem / 60, j = rem - slot*60;
    out[CLS_SZ + (size_t)n0*360 + i] = RL[rl*360 + ORD[rl*6 + slot]*60 + j];
  }
}

extern "C" void kernel_launch(void* const* d_in, const int* in_sizes, int n_in,
                              void* d_out, int out_size, void* d_ws, size_t ws_size,
                              hipStream_t stream)
{
  (void)in_sizes; (void)n_in; (void)out_size;
  const float* actors = (const float*)d_in[0];
  const float* ctrs   = (const float*)d_in[1];
  // d_in[2] = actor_idcs (identity partition; unused by the math)
  const float* pW1 = (const float*)d_in[3];
  const float* pg1 = (const float*)d_in[4];
  const float* pb1 = (const float*)d_in[5];
  const float* pW2 = (const float*)d_in[6];
  const float* pg2 = (const float*)d_in[7];
  const float* pb2 = (const float*)d_in[8];
  const float* pWo = (const float*)d_in[9];
  const float* pbo = (const float*)d_in[10];
  const float* cW1 = (const float*)d_in[11];
  const float* cg1 = (const float*)d_in[12];
  const float* cb1 = (const float*)d_in[13];
  const float* cW2 = (const float*)d_in[14];
  const float* cg2 = (const float*)d_in[15];
  const float* cb2 = (const float*)d_in[16];
  const float* cWo = (const float*)d_in[17];
  const float* cbo = (const float*)d_in[18];
  const float* dW1 = (const float*)d_in[19];
  const float* db1 = (const float*)d_in[20];
  const float* dW2 = (const float*)d_in[21];
  const float* dg2 = (const float*)d_in[22];
  const float* db2 = (const float*)d_in[23];
  const float* aW  = (const float*)d_in[24];
  const float* aG  = (const float*)d_in[25];
  const float* aB  = (const float*)d_in[26];

  float* out = (float*)d_out;
  float* out_reg = out + CLS_SZ;
  float* fws = (float*)d_ws;
  const bool split = ws_size >= FWS_FLOATS * sizeof(float);

  dim3 gA(512, 6);
  pred_kernel<<<gA, 256, 0, stream>>>(actors, ctrs, pW1, pg1, pb1, pW2, pg2, pb2,
                                      pWo, pbo, out_reg);
  if (split) {
    att_feats_kernel<<<3072, 256, 0, stream>>>(actors, ctrs,
                                               dW1, db1, dW2, dg2, db2,
                                               aW, aG, aB, out_reg, fws);
    att_cls2_kernel<<<3072, 256, 0, stream>>>(cW1, cg1, cb1, cW2, cg2, cb2,
                                              cWo, cbo, fws, out);
  } else {
    att_cls_mono_kernel<<<1536, 256, 0, stream>>>(actors, ctrs,
                                                  dW1, db1, dW2, dg2, db2,
                                                  aW, aG, aB,
                                                  cW1, cg1, cb1, cW2, cg2, cb2, cWo, cbo,
                                                  out_reg, out);
  }
  sort_kernel<<<512, 256, 0, stream>>>(out);
}

// Round 13
// 735.677 us; speedup vs baseline: 1.2704x; 1.1152x over previous
//
#include <hip/hip_runtime.h>

#define EPSV 1e-5f
#define CLS_SZ (32768*6)
#define FWS_FLOATS ((size_t)196608 * 128)

// activation LDS word index: [ch][row], 128 rows, 8-row groups XOR-swizzled by ch
#define AL(ch,row) (((ch)<<7) + ((row) ^ ((((ch)&15))<<3)))

__device__ __forceinline__ float4 ld4(const float* p) { return *reinterpret_cast<const float4*>(p); }
__device__ __forceinline__ void st4(float* p, float4 v) { *reinterpret_cast<float4*>(p) = v; }

// ---- 256-thread gemm: 8 rows x 8 cols per thread, cols {4jg..+3, 64+4jg..+3} ----
// W streamed via 4KB chunks (WB0/WB1 = 1024 floats), 8 k-rows per chunk, prefetch 2.
__device__ __forceinline__ void gemmA(const float* X, const float* __restrict__ Wg,
                                      float* WB0, float* WB1, float (&acc)[8][8],
                                      int ag, int jg4, int tid)
{
  float4 rA = ld4(Wg + tid*4);
  float4 rB = ld4(Wg + 1024 + tid*4);
  __syncthreads();
  st4(WB0 + tid*4, rA);
  st4(WB1 + tid*4, rB);
  __syncthreads();
  #pragma unroll 1
  for (int c = 0; c < 16; ++c) {
    float4 rN;
    const bool pf = (c + 2 < 16);
    if (pf) rN = ld4(Wg + (c+2)*1024 + tid*4);
    const float* WB = (c & 1) ? WB1 : WB0;
    #pragma unroll
    for (int kk = 0; kk < 8; ++kk) {
      int k = c*8 + kk;
      const float* xp = X + (k<<7) + ((ag<<3) ^ ((k & 15)<<3));
      float4 x0 = ld4(xp), x1 = ld4(xp + 4);
      float4 wl = ld4(WB + (kk<<7) + jg4);
      float4 wh = ld4(WB + (kk<<7) + 64 + jg4);
      float xv[8] = {x0.x,x0.y,x0.z,x0.w,x1.x,x1.y,x1.z,x1.w};
      float wv[8] = {wl.x,wl.y,wl.z,wl.w,wh.x,wh.y,wh.z,wh.w};
      #pragma unroll
      for (int r = 0; r < 8; ++r)
        #pragma unroll
        for (int c2 = 0; c2 < 8; ++c2)
          acc[r][c2] = fmaf(xv[r], wv[c2], acc[r][c2]);
    }
    __syncthreads();
    if (pf) st4(((c & 1) ? WB1 : WB0) + tid*4, rN);
  }
}

// output-layer gemm (pred): W [128][60] padded to [8][64] chunks; acc[8][4]
__device__ __forceinline__ void gemmWo(const float* X, const float* __restrict__ Wg,
                                       float* WB0, float* WB1, float (&acc)[8][4],
                                       int ag, int jg, int tid)
{
  const bool ld = tid < 120;
  const bool zp = (tid >= 120 && tid < 128);
  const int kk0 = ld ? (tid / 15) : (tid - 120);
  const int sl  = ld ? (tid % 15) * 4 : 60;
  float4 rA = {0,0,0,0}, rB = {0,0,0,0};
  if (ld) { rA = ld4(Wg + kk0*60 + sl); rB = ld4(Wg + 480 + kk0*60 + sl); }
  __syncthreads();
  if (ld || zp) { st4(WB0 + (kk0<<6) + sl, rA); st4(WB1 + (kk0<<6) + sl, rB); }
  __syncthreads();
  #pragma unroll 1
  for (int c = 0; c < 16; ++c) {
    float4 rN = {0,0,0,0};
    const bool pf = (c + 2 < 16);
    if (pf && ld) rN = ld4(Wg + (c+2)*480 + kk0*60 + sl);
    const float* WB = (c & 1) ? WB1 : WB0;
    #pragma unroll
    for (int kk = 0; kk < 8; ++kk) {
      int k = c*8 + kk;
      const float* xp = X + (k<<7) + ((ag<<3) ^ ((k & 15)<<3));
      float4 x0 = ld4(xp), x1 = ld4(xp + 4);
      float4 w = ld4(WB + (kk<<6) + jg*4);
      float xv[8] = {x0.x,x0.y,x0.z,x0.w,x1.x,x1.y,x1.z,x1.w};
      float wv[4] = {w.x,w.y,w.z,w.w};
      #pragma unroll
      for (int r = 0; r < 8; ++r)
        #pragma unroll
        for (int c2 = 0; c2 < 4; ++c2)
          acc[r][c2] = fmaf(xv[r], wv[c2], acc[r][c2]);
    }
    __syncthreads();
    if (pf && (ld || zp)) st4(((c & 1) ? WB1 : WB0) + (kk0<<6) + sl, rN);
  }
}

// GroupNorm(1,128) stats — R3's exact value tree; PS layout [128][4], overlaid on WB
__device__ __forceinline__ void gn_finish(float* PS1, float* PS2, float* MEAN, float* RSTD, int tid)
{
  __syncthreads();
  if (tid < 128) {
    float a = 0.f, b = 0.f;
    #pragma unroll
    for (int j = 0; j < 4; ++j) { a += PS1[tid*4 + j]; b += PS2[tid*4 + j]; }
    float mu = a * 0.0078125f;
    float var = b * 0.0078125f - mu*mu;
    MEAN[tid] = mu;
    RSTD[tid] = rsqrtf(var + EPSV);
  }
  __syncthreads();
}

__device__ __forceinline__ void gn_reduce8(const float (&acc)[8][8], float* PS1, float* PS2,
                                           float* MEAN, float* RSTD, int ag, int jg, int tid)
{
  #pragma unroll
  for (int r = 0; r < 8; ++r) {
    float s = 0.f, q = 0.f;
    #pragma unroll
    for (int c = 0; c < 8; ++c) { float v = acc[r][c]; s += v; q += v*v; }
    s += __shfl_xor(s, 1, 64); q += __shfl_xor(q, 1, 64);
    s += __shfl_xor(s, 2, 64); q += __shfl_xor(q, 2, 64);
    if ((jg & 3) == 0) { int row = ag*8 + r; PS1[row*4 + (jg>>2)] = s; PS2[row*4 + (jg>>2)] = q; }
  }
  gn_finish(PS1, PS2, MEAN, RSTD, tid);
}

// ---------------- Kernel A: per-mode pred heads -> unsorted reg ----------------
// LDS: 65536 + 8192 (WB, PS overlaid) + 1024 = 74752 B -> 2 blocks/CU
__global__ void __launch_bounds__(256, 2) pred_kernel(
    const float* __restrict__ actors, const float* __restrict__ ctrs,
    const float* __restrict__ W1, const float* __restrict__ g1v, const float* __restrict__ b1v,
    const float* __restrict__ W2, const float* __restrict__ g2v, const float* __restrict__ b2v,
    const float* __restrict__ Wo, const float* __restrict__ bov,
    float* __restrict__ out_reg)
{
  __shared__ __align__(16) float ACT[16384];
  __shared__ __align__(16) float WB0[1024], WB1[1024];
  __shared__ float MEAN[128], RSTD[128];
  float* PS1 = WB0;   // overlay: PS lifetime (post-gemm) disjoint from WB (in-gemm)
  float* PS2 = WB1;

  const int tid = threadIdx.x;
  const int jg = tid & 15, ag = tid >> 4;
  const int jg4 = jg*4;
  const int m  = blockIdx.y;
  const int n0 = blockIdx.x * 128;

  // stage actors tile (transposed+swizzled)
  #pragma unroll
  for (int p = 0; p < 16; ++p) {
    int i = (p<<8) + tid;
    int r = i >> 5, q4 = (i & 31) << 2;
    float4 v = ld4(actors + (size_t)(n0 + r)*128 + q4);
    ACT[AL(q4+0, r)] = v.x; ACT[AL(q4+1, r)] = v.y;
    ACT[AL(q4+2, r)] = v.z; ACT[AL(q4+3, r)] = v.w;
  }

  float acc[8][8];
  #pragma unroll
  for (int r = 0; r < 8; ++r)
    #pragma unroll
    for (int c = 0; c < 8; ++c) acc[r][c] = 0.f;

  // L1: relu(GN(actors @ W1)) -> ACT
  gemmA(ACT, W1 + (size_t)m*16384, WB0, WB1, acc, ag, jg4, tid);
  gn_reduce8(acc, PS1, PS2, MEAN, RSTD, ag, jg, tid);
  {
    float mu[8], rs[8];
    #pragma unroll
    for (int r = 0; r < 8; ++r) { mu[r] = MEAN[ag*8+r]; rs[r] = RSTD[ag*8+r]; }
    float4 gl = ld4(g1v + m*128 + jg4), gh = ld4(g1v + m*128 + 64 + jg4);
    float4 bl = ld4(b1v + m*128 + jg4), bh = ld4(b1v + m*128 + 64 + jg4);
    float gv[8] = {gl.x,gl.y,gl.z,gl.w,gh.x,gh.y,gh.z,gh.w};
    float bv[8] = {bl.x,bl.y,bl.z,bl.w,bh.x,bh.y,bh.z,bh.w};
    float vm[8][8];
    #pragma unroll
    for (int r = 0; r < 8; ++r)
      #pragma unroll
      for (int c = 0; c < 8; ++c)
        vm[r][c] = fmaxf((acc[r][c] - mu[r]) * rs[r] * gv[c] + bv[c], 0.f);
    #pragma unroll
    for (int c = 0; c < 8; ++c) {
      int ch = (c < 4) ? (jg4 + c) : (64 + jg4 + (c - 4));
      int base = (ch<<7) + ((ag<<3) ^ ((ch & 15)<<3));
      st4(ACT + base,     make_float4(vm[0][c],vm[1][c],vm[2][c],vm[3][c]));
      st4(ACT + base + 4, make_float4(vm[4][c],vm[5][c],vm[6][c],vm[7][c]));
    }
  }

  #pragma unroll
  for (int r = 0; r < 8; ++r)
    #pragma unroll
    for (int c = 0; c < 8; ++c) acc[r][c] = 0.f;

  // L2: relu(GN(h1 @ W2) + actors) -> ACT
  gemmA(ACT, W2 + (size_t)m*16384, WB0, WB1, acc, ag, jg4, tid);
  gn_reduce8(acc, PS1, PS2, MEAN, RSTD, ag, jg, tid);
  {
    float mu[8], rs[8];
    #pragma unroll
    for (int r = 0; r < 8; ++r) { mu[r] = MEAN[ag*8+r]; rs[r] = RSTD[ag*8+r]; }
    float4 gl = ld4(g2v + m*128 + jg4), gh = ld4(g2v + m*128 + 64 + jg4);
    float4 bl = ld4(b2v + m*128 + jg4), bh = ld4(b2v + m*128 + 64 + jg4);
    float gv[8] = {gl.x,gl.y,gl.z,gl.w,gh.x,gh.y,gh.z,gh.w};
    float bv[8] = {bl.x,bl.y,bl.z,bl.w,bh.x,bh.y,bh.z,bh.w};
    float vm[8][8];
    #pragma unroll
    for (int r = 0; r < 8; ++r) {
      const float* ap = actors + (size_t)(n0 + ag*8 + r)*128;
      float4 a0 = ld4(ap + jg4), a1 = ld4(ap + 64 + jg4);
      float av[8] = {a0.x,a0.y,a0.z,a0.w,a1.x,a1.y,a1.z,a1.w};
      #pragma unroll
      for (int c = 0; c < 8; ++c)
        vm[r][c] = fmaxf((acc[r][c] - mu[r]) * rs[r] * gv[c] + bv[c] + av[c], 0.f);
    }
    #pragma unroll
    for (int c = 0; c < 8; ++c) {
      int ch = (c < 4) ? (jg4 + c) : (64 + jg4 + (c - 4));
      int base = (ch<<7) + ((ag<<3) ^ ((ch & 15)<<3));
      st4(ACT + base,     make_float4(vm[0][c],vm[1][c],vm[2][c],vm[3][c]));
      st4(ACT + base + 4, make_float4(vm[4][c],vm[5][c],vm[6][c],vm[7][c]));
    }
  }

  // L3: h @ Wo + bo + ctr -> reg
  float acc2[8][4];
  #pragma unroll
  for (int r = 0; r < 8; ++r)
    #pragma unroll
    for (int c = 0; c < 4; ++c) acc2[r][c] = 0.f;
  gemmWo(ACT, Wo + (size_t)m*7680, WB0, WB1, acc2, ag, jg, tid);

  if (jg < 15) {
    float4 bo4 = ld4(bov + m*60 + jg4);
    #pragma unroll
    for (int r = 0; r < 8; ++r) {
      int n = n0 + ag*8 + r;
      float2 cc = *reinterpret_cast<const float2*>(ctrs + 2*n);
      float4 v;
      v.x = acc2[r][0] + bo4.x + cc.x;
      v.y = acc2[r][1] + bo4.y + cc.y;
      v.z = acc2[r][2] + bo4.z + cc.x;
      v.w = acc2[r][3] + bo4.w + cc.y;
      st4(out_reg + (size_t)n*360 + m*60 + jg4, v);
    }
  }
}

// ---------------- Kernel B: AttDest + cls head, feats staged via ws ----------------
// WS=true: feats round-trips through fws (no register spill).
// WS=false: R8 behavior (feats in regs) — fallback when ws too small.
template<bool WS>
__global__ void __launch_bounds__(256, 2) att_cls_kernel(
    const float* __restrict__ actors, const float* __restrict__ ctrs,
    const float* __restrict__ dW1, const float* __restrict__ db1,
    const float* __restrict__ dW2, const float* __restrict__ dg2, const float* __restrict__ db2,
    const float* __restrict__ aW, const float* __restrict__ aG, const float* __restrict__ aB,
    const float* __restrict__ cW1, const float* __restrict__ cg1, const float* __restrict__ cb1,
    const float* __restrict__ cW2, const float* __restrict__ cg2, const float* __restrict__ cb2,
    const float* __restrict__ cWo, const float* __restrict__ cbo,
    const float* __restrict__ reg, float* __restrict__ fws,
    float* __restrict__ cls_out)
{
  __shared__ __align__(16) float ACT[16384];
  __shared__ __align__(16) float WB0[1024], WB1[1024];
  __shared__ float MEAN[128], RSTD[128];
  float* PS1 = WB0;
  float* PS2 = WB1;
  float* D0x = MEAN;  // D0 consumed in P1, MEAN/RSTD first written in P2's gn
  float* D0y = RSTD;

  const int tid = threadIdx.x;
  const int jg = tid & 15, ag = tid >> 4;   // rows ag*8..+7
  const int jg4 = jg*4;
  const int r0 = blockIdx.x * 128;

  // P0: dist0 = ctr - reg_last
  if (tid < 128) {
    int rg = r0 + tid;
    int n = rg / 6, mm = rg - 6*n;
    size_t base = (size_t)n*360 + mm*60;
    float2 c2 = *reinterpret_cast<const float2*>(ctrs + 2*n);
    D0x[tid] = c2.x - reg[base + 58];
    D0y[tid] = c2.y - reg[base + 59];
  }
  __syncthreads();

  // P1: dist1 = relu(dist0 @ dW1 + db1) -> ACT
  {
    float dx[8], dy[8];
    #pragma unroll
    for (int r = 0; r < 8; ++r) { dx[r] = D0x[ag*8+r]; dy[r] = D0y[ag*8+r]; }
    #pragma unroll
    for (int c = 0; c < 8; ++c) {
      int ch = (c < 4) ? (jg4 + c) : (64 + jg4 + (c - 4));
      float w1 = dW1[ch], w2 = dW1[128 + ch], bb = db1[ch];
      float v[8];
      #pragma unroll
      for (int r = 0; r < 8; ++r) v[r] = fmaxf(fmaf(dx[r], w1, fmaf(dy[r], w2, bb)), 0.f);
      int base = (ch<<7) + ((ag<<3) ^ ((ch & 15)<<3));
      st4(ACT + base,     make_float4(v[0],v[1],v[2],v[3]));
      st4(ACT + base + 4, make_float4(v[4],v[5],v[6],v[7]));
    }
  }

  float acc[8][8];
  #pragma unroll
  for (int r = 0; r < 8; ++r)
    #pragma unroll
    for (int c = 0; c < 8; ++c) acc[r][c] = 0.f;

  // P2: dist2 = relu(GN(dist1 @ dW2)) -> ACT
  gemmA(ACT, dW2, WB0, WB1, acc, ag, jg4, tid);
  gn_reduce8(acc, PS1, PS2, MEAN, RSTD, ag, jg, tid);
  {
    float mu[8], rs[8];
    #pragma unroll
    for (int r = 0; r < 8; ++r) { mu[r] = MEAN[ag*8+r]; rs[r] = RSTD[ag*8+r]; }
    float4 gl = ld4(dg2 + jg4), gh = ld4(dg2 + 64 + jg4);
    float4 bl = ld4(db2 + jg4), bh = ld4(db2 + 64 + jg4);
    float gv[8] = {gl.x,gl.y,gl.z,gl.w,gh.x,gh.y,gh.z,gh.w};
    float bv[8] = {bl.x,bl.y,bl.z,bl.w,bh.x,bh.y,bh.z,bh.w};
    float vm[8][8];
    #pragma unroll
    for (int r = 0; r < 8; ++r)
      #pragma unroll
      for (int c = 0; c < 8; ++c)
        vm[r][c] = fmaxf((acc[r][c] - mu[r]) * rs[r] * gv[c] + bv[c], 0.f);
    #pragma unroll
    for (int c = 0; c < 8; ++c) {
      int ch = (c < 4) ? (jg4 + c) : (64 + jg4 + (c - 4));
      int base = (ch<<7) + ((ag<<3) ^ ((ch & 15)<<3));
      st4(ACT + base,     make_float4(vm[0][c],vm[1][c],vm[2][c],vm[3][c]));
      st4(ACT + base + 4, make_float4(vm[4][c],vm[5][c],vm[6][c],vm[7][c]));
    }
  }

  // P3: feats = relu(GN(dist2 @ aW_lo + agts @ aW_hi)) -> ACT (+ fws or regs)
  #pragma unroll
  for (int r = 0; r < 8; ++r)
    #pragma unroll
    for (int c = 0; c < 8; ++c) acc[r][c] = 0.f;
  gemmA(ACT, aW, WB0, WB1, acc, ag, jg4, tid);
  // restage agts into ACT (gemmA's trailing barrier ended all dist2 reads;
  // next gemmA's staging barrier precedes any ACT read)
  #pragma unroll
  for (int p = 0; p < 16; ++p) {
    int i = (p<<8) + tid;
    int r = i >> 5, q4 = (i & 31) << 2;
    int n = (r0 + r) / 6;
    float4 v = ld4(actors + (size_t)n*128 + q4);
    ACT[AL(q4+0, r)] = v.x; ACT[AL(q4+1, r)] = v.y;
    ACT[AL(q4+2, r)] = v.z; ACT[AL(q4+3, r)] = v.w;
  }
  gemmA(ACT, aW + 16384, WB0, WB1, acc, ag, jg4, tid);
  gn_reduce8(acc, PS1, PS2, MEAN, RSTD, ag, jg, tid);
  float featr[8][8];   // only persists across P4 when !WS
  {
    float mu[8], rs[8];
    #pragma unroll
    for (int r = 0; r < 8; ++r) { mu[r] = MEAN[ag*8+r]; rs[r] = RSTD[ag*8+r]; }
    float4 gl = ld4(aG + jg4), gh = ld4(aG + 64 + jg4);
    float4 bl = ld4(aB + jg4), bh = ld4(aB + 64 + jg4);
    float gv[8] = {gl.x,gl.y,gl.z,gl.w,gh.x,gh.y,gh.z,gh.w};
    float bv[8] = {bl.x,bl.y,bl.z,bl.w,bh.x,bh.y,bh.z,bh.w};
    #pragma unroll
    for (int r = 0; r < 8; ++r)
      #pragma unroll
      for (int c = 0; c < 8; ++c)
        featr[r][c] = fmaxf((acc[r][c] - mu[r]) * rs[r] * gv[c] + bv[c], 0.f);
    #pragma unroll
    for (int c = 0; c < 8; ++c) {
      int ch = (c < 4) ? (jg4 + c) : (64 + jg4 + (c - 4));
      int base = (ch<<7) + ((ag<<3) ^ ((ch & 15)<<3));
      st4(ACT + base,     make_float4(featr[0][c],featr[1][c],featr[2][c],featr[3][c]));
      st4(ACT + base + 4, make_float4(featr[4][c],featr[5][c],featr[6][c],featr[7][c]));
    }
    if (WS) {
      #pragma unroll
      for (int r = 0; r < 8; ++r) {
        float* fp = fws + (size_t)(r0 + ag*8 + r)*128;
        st4(fp + jg4,      make_float4(featr[r][0],featr[r][1],featr[r][2],featr[r][3]));
        st4(fp + 64 + jg4, make_float4(featr[r][4],featr[r][5],featr[r][6],featr[r][7]));
      }
    }
  }

  // P4: c1 = relu(GN(feats @ cls_W1)) -> ACT
  #pragma unroll
  for (int r = 0; r < 8; ++r)
    #pragma unroll
    for (int c = 0; c < 8; ++c) acc[r][c] = 0.f;
  gemmA(ACT, cW1, WB0, WB1, acc, ag, jg4, tid);
  gn_reduce8(acc, PS1, PS2, MEAN, RSTD, ag, jg, tid);
  {
    float mu[8], rs[8];
    #pragma unroll
    for (int r = 0; r < 8; ++r) { mu[r] = MEAN[ag*8+r]; rs[r] = RSTD[ag*8+r]; }
    float4 gl = ld4(cg1 + jg4), gh = ld4(cg1 + 64 + jg4);
    float4 bl = ld4(cb1 + jg4), bh = ld4(cb1 + 64 + jg4);
    float gv[8] = {gl.x,gl.y,gl.z,gl.w,gh.x,gh.y,gh.z,gh.w};
    float bv[8] = {bl.x,bl.y,bl.z,bl.w,bh.x,bh.y,bh.z,bh.w};
    float vm[8][8];
    #pragma unroll
    for (int r = 0; r < 8; ++r)
      #pragma unroll
      for (int c = 0; c < 8; ++c)
        vm[r][c] = fmaxf((acc[r][c] - mu[r]) * rs[r] * gv[c] + bv[c], 0.f);
    #pragma unroll
    for (int c = 0; c < 8; ++c) {
      int ch = (c < 4) ? (jg4 + c) : (64 + jg4 + (c - 4));
      int base = (ch<<7) + ((ag<<3) ^ ((ch & 15)<<3));
      st4(ACT + base,     make_float4(vm[0][c],vm[1][c],vm[2][c],vm[3][c]));
      st4(ACT + base + 4, make_float4(vm[4][c],vm[5][c],vm[6][c],vm[7][c]));
    }
  }

  // P5: c2 = GN(c1 @ cls_W2); c = relu(c2 + feats); cls = c @ cls_Wo + bo
  #pragma unroll
  for (int r = 0; r < 8; ++r)
    #pragma unroll
    for (int c = 0; c < 8; ++c) acc[r][c] = 0.f;
  gemmA(ACT, cW2, WB0, WB1, acc, ag, jg4, tid);
  gn_reduce8(acc, PS1, PS2, MEAN, RSTD, ag, jg, tid);
  {
    float mu[8], rs[8];
    #pragma unroll
    for (int r = 0; r < 8; ++r) { mu[r] = MEAN[ag*8+r]; rs[r] = RSTD[ag*8+r]; }
    float4 gl = ld4(cg2 + jg4), gh = ld4(cg2 + 64 + jg4);
    float4 bl = ld4(cb2 + jg4), bh = ld4(cb2 + 64 + jg4);
    float4 wl = ld4(cWo + jg4), wh = ld4(cWo + 64 + jg4);
    float gv[8] = {gl.x,gl.y,gl.z,gl.w,gh.x,gh.y,gh.z,gh.w};
    float bv[8] = {bl.x,bl.y,bl.z,bl.w,bh.x,bh.y,bh.z,bh.w};
    float wv[8] = {wl.x,wl.y,wl.z,wl.w,wh.x,wh.y,wh.z,wh.w};
    #pragma unroll
    for (int r = 0; r < 8; ++r) {
      float av[8];
      if (WS) {
        const float* fp = fws + (size_t)(r0 + ag*8 + r)*128;
        float4 a0 = ld4(fp + jg4), a1 = ld4(fp + 64 + jg4);
        av[0]=a0.x; av[1]=a0.y; av[2]=a0.z; av[3]=a0.w;
        av[4]=a1.x; av[5]=a1.y; av[6]=a1.z; av[7]=a1.w;
      } else {
        #pragma unroll
        for (int c = 0; c < 8; ++c) av[c] = featr[r][c];
      }
      float p = 0.f;
      #pragma unroll
      for (int c = 0; c < 8; ++c) {
        float v = (acc[r][c] - mu[r]) * rs[r] * gv[c] + bv[c];
        v = fmaxf(v + av[c], 0.f);
        p = fmaf(v, wv[c], p);
      }
      float s = p;
      s += __shfl_xor(s, 1, 64);
      s += __shfl_xor(s, 2, 64);
      if ((jg & 3) == 0) PS1[(ag*8+r)*4 + (jg>>2)] = s;
    }
  }
  __syncthreads();
  if (tid < 128) {
    float s = 0.f;
    #pragma unroll
    for (int j = 0; j < 4; ++j) s += PS1[tid*4 + j];
    cls_out[r0 + tid] = s + cbo[0];
  }
}

// ---------------- Kernel C: per-actor stable descending sort + permute ----------------
__global__ void __launch_bounds__(256) sort_kernel(float* __restrict__ out)
{
  __shared__ float RL[64*360];
  __shared__ float CL[64*6];
  __shared__ float CS[64*6];
  __shared__ int   ORD[64*6];

  const int tid = threadIdx.x;
  const int n0 = blockIdx.x * 64;
  float* regp = out + CLS_SZ;

  for (int i = tid; i < 64*360; i += 256) RL[i] = regp[(size_t)n0*360 + i];
  for (int i = tid; i < 384; i += 256)    CL[i] = out[n0*6 + i];
  __syncthreads();

  if (tid < 64) {
    float v[6];
    #pragma unroll
    for (int m2 = 0; m2 < 6; ++m2) v[m2] = CL[tid*6 + m2];
    int used = 0;
    for (int j = 0; j < 6; ++j) {
      int best = -1; float bv = 0.f;
      for (int m2 = 0; m2 < 6; ++m2) {
        if (used & (1 << m2)) continue;
        if (best < 0 || v[m2] > bv) { best = m2; bv = v[m2]; }  // stable: strict >
      }
      used |= (1 << best);
      ORD[tid*6 + j] = best;
      CS[tid*6 + j] = bv;
    }
  }
  __syncthreads();

  for (int i = tid; i < 384; i += 256) out[n0*6 + i] = CS[i];
  for (int i = tid; i < 64*360; i += 256) {
    int rl = i / 360, rem = i - rl*360;
    int slot = rem / 60, j = rem - slot*60;
    out[CLS_SZ + (size_t)n0*360 + i] = RL[rl*360 + ORD[rl*6 + slot]*60 + j];
  }
}

extern "C" void kernel_launch(void* const* d_in, const int* in_sizes, int n_in,
                              void* d_out, int out_size, void* d_ws, size_t ws_size,
                              hipStream_t stream)
{
  (void)in_sizes; (void)n_in; (void)out_size;
  const float* actors = (const float*)d_in[0];
  const float* ctrs   = (const float*)d_in[1];
  // d_in[2] = actor_idcs (identity partition; unused by the math)
  const float* pW1 = (const float*)d_in[3];
  const float* pg1 = (const float*)d_in[4];
  const float* pb1 = (const float*)d_in[5];
  const float* pW2 = (const float*)d_in[6];
  const float* pg2 = (const float*)d_in[7];
  const float* pb2 = (const float*)d_in[8];
  const float* pWo = (const float*)d_in[9];
  const float* pbo = (const float*)d_in[10];
  const float* cW1 = (const float*)d_in[11];
  const float* cg1 = (const float*)d_in[12];
  const float* cb1 = (const float*)d_in[13];
  const float* cW2 = (const float*)d_in[14];
  const float* cg2 = (const float*)d_in[15];
  const float* cb2 = (const float*)d_in[16];
  const float* cWo = (const float*)d_in[17];
  const float* cbo = (const float*)d_in[18];
  const float* dW1 = (const float*)d_in[19];
  const float* db1 = (const float*)d_in[20];
  const float* dW2 = (const float*)d_in[21];
  const float* dg2 = (const float*)d_in[22];
  const float* db2 = (const float*)d_in[23];
  const float* aW  = (const float*)d_in[24];
  const float* aG  = (const float*)d_in[25];
  const float* aB  = (const float*)d_in[26];

  float* out = (float*)d_out;
  float* out_reg = out + CLS_SZ;
  float* fws = (float*)d_ws;
  const bool ws_ok = ws_size >= FWS_FLOATS * sizeof(float);

  dim3 gA(256, 6);
  pred_kernel<<<gA, 256, 0, stream>>>(actors, ctrs, pW1, pg1, pb1, pW2, pg2, pb2,
                                      pWo, pbo, out_reg);
  if (ws_ok) {
    att_cls_kernel<true><<<1536, 256, 0, stream>>>(actors, ctrs,
                                                   dW1, db1, dW2, dg2, db2,
                                                   aW, aG, aB,
                                                   cW1, cg1, cb1, cW2, cg2, cb2, cWo, cbo,
                                                   out_reg, fws, out);
  } else {
    att_cls_kernel<false><<<1536, 256, 0, stream>>>(actors, ctrs,
                                                    dW1, db1, dW2, dg2, db2,
                                                    aW, aG, aB,
                                                    cW1, cg1, cb1, cW2, cg2, cb2, cWo, cbo,
                                                    out_reg, nullptr, out);
  }
  sort_kernel<<<512, 256, 0, stream>>>(out);
}